// Round 1
// baseline (3098.672 us; speedup 1.0000x reference)
//
#include <hip/hip_runtime.h>

#define B  4
#define T  2048
#define D  1024
#define NH 16
#define DH 64

// ---------------------------------------------------------------------------
// C(M,N) = A(M,K) @ Bm(K,N), all row-major fp32. BM=BN=64, BK=16, 256 thr,
// each thread computes a 4x4 block. Dims assumed divisible by tile sizes.
// ---------------------------------------------------------------------------
template<int BM, int BN, int BK>
__global__ __launch_bounds__(256)
void gemm_f32(const float* __restrict__ A, const float* __restrict__ Bm,
              float* __restrict__ C, int M, int N, int K) {
    __shared__ float As[BK][BM];   // transposed A tile
    __shared__ float Bs[BK][BN];
    const int tid = threadIdx.x;
    const int bm = blockIdx.y * BM;
    const int bn = blockIdx.x * BN;
    const int tx = tid & 15;       // 0..15  -> N direction
    const int ty = tid >> 4;       // 0..15  -> M direction
    float c[4][4] = {};

    for (int k0 = 0; k0 < K; k0 += BK) {
        // A tile: 64 rows x 16 k. 256 threads x 1 float4 = 1024 floats.
        {
            const int row = tid >> 2;          // 0..63
            const int col = (tid & 3) * 4;     // 0,4,8,12
            const float4 a4 = *(const float4*)&A[(size_t)(bm + row) * K + k0 + col];
            As[col + 0][row] = a4.x;
            As[col + 1][row] = a4.y;
            As[col + 2][row] = a4.z;
            As[col + 3][row] = a4.w;
        }
        // B tile: 16 k x 64 cols.
        {
            const int row = tid >> 4;          // 0..15
            const int col = (tid & 15) * 4;
            *(float4*)&Bs[row][col] = *(const float4*)&Bm[(size_t)(k0 + row) * N + bn + col];
        }
        __syncthreads();
        #pragma unroll
        for (int kk = 0; kk < BK; ++kk) {
            const float4 a4 = *(const float4*)&As[kk][ty * 4];
            const float4 b4 = *(const float4*)&Bs[kk][tx * 4];
            const float a[4] = {a4.x, a4.y, a4.z, a4.w};
            const float b[4] = {b4.x, b4.y, b4.z, b4.w};
            #pragma unroll
            for (int i = 0; i < 4; ++i)
                #pragma unroll
                for (int j = 0; j < 4; ++j)
                    c[i][j] += a[i] * b[j];
        }
        __syncthreads();
    }
    #pragma unroll
    for (int i = 0; i < 4; ++i) {
        const float4 out = {c[i][0], c[i][1], c[i][2], c[i][3]};
        *(float4*)&C[(size_t)(bm + ty * 4 + i) * N + bn + tx * 4] = out;
    }
}

// ---------------------------------------------------------------------------
// Flash-style attention, fp32. qkv layout: (B*T, 3*D) row-major; per row:
// [q(D) | k(D) | v(D)], head h occupies cols h*DH..h*DH+63 of each section.
// One thread per query row (q, o in registers). K/V tiles of 64 keys in LDS.
// Online softmax with per-16-key max updates. Output y: (B*T, D) head-merged.
// ---------------------------------------------------------------------------
__global__ __launch_bounds__(256)
void attn_f32(const float* __restrict__ qkv, float* __restrict__ y) {
    const int bh = blockIdx.y;
    const int b  = bh / NH;
    const int h  = bh % NH;
    const int t  = blockIdx.x * 256 + threadIdx.x;
    const float scale = 0.125f;                 // 1/sqrt(DH)

    __shared__ float Kt[64][DH];
    __shared__ float Vt[64][DH];

    float q[DH];
    {
        const size_t qbase = (size_t)(b * T + t) * (3 * D) + h * DH;
        #pragma unroll
        for (int d4 = 0; d4 < DH / 4; ++d4) {
            const float4 v4 = *(const float4*)&qkv[qbase + d4 * 4];
            q[d4 * 4 + 0] = v4.x; q[d4 * 4 + 1] = v4.y;
            q[d4 * 4 + 2] = v4.z; q[d4 * 4 + 3] = v4.w;
        }
    }
    float o[DH];
    #pragma unroll
    for (int d = 0; d < DH; ++d) o[d] = 0.f;
    float m = -1e30f, l = 0.f;

    for (int kt = 0; kt < T; kt += 64) {
        __syncthreads();
        // stage K and V tiles: each 64x64 floats = 1024 float4; 4 per thread.
        #pragma unroll
        for (int it = 0; it < 4; ++it) {
            const int e   = threadIdx.x + 256 * it;   // 0..1023
            const int row = e >> 4;                   // 0..63
            const int c4  = (e & 15) * 4;
            const size_t src = (size_t)(b * T + kt + row) * (3 * D) + D + h * DH + c4;
            *(float4*)&Kt[row][c4] = *(const float4*)&qkv[src];
            *(float4*)&Vt[row][c4] = *(const float4*)&qkv[src + D];
        }
        __syncthreads();

        #pragma unroll 1
        for (int j0 = 0; j0 < 64; j0 += 16) {
            float s[16];
            float smax = -1e30f;
            #pragma unroll
            for (int jj = 0; jj < 16; ++jj) {
                float acc = 0.f;
                #pragma unroll
                for (int d4 = 0; d4 < DH / 4; ++d4) {
                    const float4 k4 = *(const float4*)&Kt[j0 + jj][d4 * 4];
                    acc += q[d4 * 4 + 0] * k4.x + q[d4 * 4 + 1] * k4.y
                         + q[d4 * 4 + 2] * k4.z + q[d4 * 4 + 3] * k4.w;
                }
                s[jj] = acc * scale;
                smax = fmaxf(smax, s[jj]);
            }
            const float mnew = fmaxf(m, smax);
            const float corr = __expf(m - mnew);
            l *= corr;
            #pragma unroll
            for (int d = 0; d < DH; ++d) o[d] *= corr;
            #pragma unroll
            for (int jj = 0; jj < 16; ++jj) {
                const float p = __expf(s[jj] - mnew);
                l += p;
                #pragma unroll
                for (int d4 = 0; d4 < DH / 4; ++d4) {
                    const float4 v4 = *(const float4*)&Vt[j0 + jj][d4 * 4];
                    o[d4 * 4 + 0] += p * v4.x; o[d4 * 4 + 1] += p * v4.y;
                    o[d4 * 4 + 2] += p * v4.z; o[d4 * 4 + 3] += p * v4.w;
                }
            }
            m = mnew;
        }
    }

    const float inv_l = 1.0f / l;
    const size_t ybase = (size_t)(b * T + t) * D + h * DH;
    #pragma unroll
    for (int d4 = 0; d4 < DH / 4; ++d4) {
        const float4 out = {o[d4 * 4 + 0] * inv_l, o[d4 * 4 + 1] * inv_l,
                            o[d4 * 4 + 2] * inv_l, o[d4 * 4 + 3] * inv_l};
        *(float4*)&y[ybase + d4 * 4] = out;
    }
}

// ---------------------------------------------------------------------------
extern "C" void kernel_launch(void* const* d_in, const int* in_sizes, int n_in,
                              void* d_out, int out_size, void* d_ws, size_t ws_size,
                              hipStream_t stream) {
    const float* x     = (const float*)d_in[0];   // (B,T,D)
    const float* w_qkv = (const float*)d_in[1];   // (D,3D)
    const float* w_out = (const float*)d_in[2];   // (D,D)
    float* out = (float*)d_out;                   // (B,T,D)

    float* qkv = (float*)d_ws;                        // (B*T, 3D)  100.7 MB
    float* y   = qkv + (size_t)B * T * 3 * D;         // (B*T, D)    33.5 MB

    // 1) qkv = x @ w_qkv
    gemm_f32<64, 64, 16><<<dim3((3 * D) / 64, (B * T) / 64), 256, 0, stream>>>(
        x, w_qkv, qkv, B * T, 3 * D, D);
    // 2) y = softmax(q k^T / sqrt(DH)) v   (head-merged output)
    attn_f32<<<dim3(T / 256, B * NH), 256, 0, stream>>>(qkv, y);
    // 3) out = y @ w_out
    gemm_f32<64, 64, 16><<<dim3(D / 64, (B * T) / 64), 256, 0, stream>>>(
        y, w_out, out, B * T, D, D);
}

// Round 3
// 1229.592 us; speedup vs baseline: 2.5201x; 2.5201x over previous
//
#include <hip/hip_runtime.h>

#define B  4
#define T  2048
#define D  1024
#define NH 16
#define DH 64

typedef __attribute__((ext_vector_type(8))) short bf16x8;
typedef __attribute__((ext_vector_type(4))) float f32x4;

__device__ inline unsigned short f2bf(float f) {
    union { float f; unsigned int u; } v; v.f = f;
    unsigned int r = v.u + 0x7fff + ((v.u >> 16) & 1);   // RNE
    return (unsigned short)(r >> 16);
}

// ---------------------------------------------------------------------------
// fp32 GEMM (unchanged this round): C(M,N) = A(M,K) @ Bm(K,N), row-major.
// ---------------------------------------------------------------------------
template<int BM, int BN, int BK>
__global__ __launch_bounds__(256)
void gemm_f32(const float* __restrict__ A, const float* __restrict__ Bm,
              float* __restrict__ C, int M, int N, int K) {
    __shared__ float As[BK][BM];
    __shared__ float Bs[BK][BN];
    const int tid = threadIdx.x;
    const int bm = blockIdx.y * BM;
    const int bn = blockIdx.x * BN;
    const int tx = tid & 15;
    const int ty = tid >> 4;
    float c[4][4] = {};

    for (int k0 = 0; k0 < K; k0 += BK) {
        {
            const int row = tid >> 2;
            const int col = (tid & 3) * 4;
            const float4 a4 = *(const float4*)&A[(size_t)(bm + row) * K + k0 + col];
            As[col + 0][row] = a4.x;
            As[col + 1][row] = a4.y;
            As[col + 2][row] = a4.z;
            As[col + 3][row] = a4.w;
        }
        {
            const int row = tid >> 4;
            const int col = (tid & 15) * 4;
            *(float4*)&Bs[row][col] = *(const float4*)&Bm[(size_t)(k0 + row) * N + bn + col];
        }
        __syncthreads();
        #pragma unroll
        for (int kk = 0; kk < BK; ++kk) {
            const float4 a4 = *(const float4*)&As[kk][ty * 4];
            const float4 b4 = *(const float4*)&Bs[kk][tx * 4];
            const float a[4] = {a4.x, a4.y, a4.z, a4.w};
            const float b[4] = {b4.x, b4.y, b4.z, b4.w};
            #pragma unroll
            for (int i = 0; i < 4; ++i)
                #pragma unroll
                for (int j = 0; j < 4; ++j)
                    c[i][j] += a[i] * b[j];
        }
        __syncthreads();
    }
    #pragma unroll
    for (int i = 0; i < 4; ++i) {
        const float4 out = {c[i][0], c[i][1], c[i][2], c[i][3]};
        *(float4*)&C[(size_t)(bm + ty * 4 + i) * N + bn + tx * 4] = out;
    }
}

// ---------------------------------------------------------------------------
// bf16-MFMA flash attention. qkv (B*T, 3D) fp32: per row [q|k|v], head h at
// cols h*DH. Block = 256 thr (4 waves), Q-tile 64 rows (16/wave), KV-tile 64.
// Q pre-scaled by 1/sqrt(DH) at staging. fp32 softmax + accumulators.
// LDS tiles XOR-swizzled: byte ^= (row&7)<<4 (rows are 128B).
// ---------------------------------------------------------------------------
__global__ __launch_bounds__(256)
void attn_mfma(const float* __restrict__ qkv, float* __restrict__ y) {
    const int bh  = blockIdx.y;
    const int b   = bh / NH;
    const int h   = bh % NH;
    const int qt  = blockIdx.x;
    const int tid = threadIdx.x;
    const int w    = tid >> 6;
    const int lane = tid & 63;
    const int lq   = lane & 15;     // MFMA m/n index
    const int lk   = lane >> 4;     // MFMA k-slice index (0..3)

    __shared__ unsigned char Ks [64 * 128];  // bf16 [key][dh], swizzled
    __shared__ unsigned char Vts[64 * 128];  // bf16 [dh][key], swizzled
    __shared__ unsigned char QPs[64 * 128];  // Q tile, then per-wave P (w*2048)

    // ---- stage Q (pre-scaled), fp32 -> bf16, swizzled ----
    #pragma unroll
    for (int it = 0; it < 4; ++it) {
        const int e   = tid + 256 * it;
        const int row = e >> 4;
        const int c4  = (e & 15) * 4;
        const float4 v4 = *(const float4*)&qkv[(size_t)(b * T + qt * 64 + row) * (3 * D) + h * DH + c4];
        ushort4 bv = { f2bf(v4.x * 0.125f), f2bf(v4.y * 0.125f),
                       f2bf(v4.z * 0.125f), f2bf(v4.w * 0.125f) };
        const int off = (row * 128 + c4 * 2) ^ ((row & 7) << 4);
        *(ushort4*)&QPs[off] = bv;
    }
    __syncthreads();

    // ---- Q A-fragments into registers (2 k-slices of 32) ----
    bf16x8 qf[2];
    #pragma unroll
    for (int ks = 0; ks < 2; ++ks) {
        const int row = w * 16 + lq;
        const int off = (row * 128 + ks * 64 + lk * 16) ^ ((row & 7) << 4);
        qf[ks] = *(const bf16x8*)&QPs[off];
    }

    f32x4 o[4];
    #pragma unroll
    for (int dt = 0; dt < 4; ++dt) o[dt] = f32x4{0.f, 0.f, 0.f, 0.f};
    float m_r[4] = {-1e30f, -1e30f, -1e30f, -1e30f};
    float l_r[4] = {0.f, 0.f, 0.f, 0.f};

    unsigned char* Pw = &QPs[w * 2048];

    for (int kt = 0; kt < T; kt += 64) {
        __syncthreads();   // previous tile fully consumed
        // ---- stage K tile ----
        #pragma unroll
        for (int it = 0; it < 4; ++it) {
            const int e   = tid + 256 * it;
            const int row = e >> 4;          // key
            const int c4  = (e & 15) * 4;    // dh
            const float4 v4 = *(const float4*)&qkv[(size_t)(b * T + kt + row) * (3 * D) + D + h * DH + c4];
            ushort4 bv = { f2bf(v4.x), f2bf(v4.y), f2bf(v4.z), f2bf(v4.w) };
            const int off = (row * 128 + c4 * 2) ^ ((row & 7) << 4);
            *(ushort4*)&Ks[off] = bv;
        }
        // ---- stage V transposed: Vt[dh][key] ----
        {
            const int key = tid & 63;
            const int dh0 = (tid >> 6) * 16;
            const float* vsrc = &qkv[(size_t)(b * T + kt + key) * (3 * D) + 2 * D + h * DH + dh0];
            #pragma unroll
            for (int it = 0; it < 4; ++it) {
                const float4 v4 = *(const float4*)&vsrc[it * 4];
                const int dh = dh0 + it * 4;
                *(unsigned short*)&Vts[((dh + 0) * 128 + key * 2) ^ (((dh + 0) & 7) << 4)] = f2bf(v4.x);
                *(unsigned short*)&Vts[((dh + 1) * 128 + key * 2) ^ (((dh + 1) & 7) << 4)] = f2bf(v4.y);
                *(unsigned short*)&Vts[((dh + 2) * 128 + key * 2) ^ (((dh + 2) & 7) << 4)] = f2bf(v4.z);
                *(unsigned short*)&Vts[((dh + 3) * 128 + key * 2) ^ (((dh + 3) & 7) << 4)] = f2bf(v4.w);
            }
        }
        __syncthreads();

        // ---- S = Q K^T (scaled): 4 key sub-tiles x 2 k-slices ----
        f32x4 s[4];
        #pragma unroll
        for (int ct = 0; ct < 4; ++ct) s[ct] = f32x4{0.f, 0.f, 0.f, 0.f};
        #pragma unroll
        for (int ks = 0; ks < 2; ++ks) {
            #pragma unroll
            for (int ct = 0; ct < 4; ++ct) {
                const int key = ct * 16 + lq;
                const int off = (key * 128 + ks * 64 + lk * 16) ^ ((key & 7) << 4);
                const bf16x8 kf = *(const bf16x8*)&Ks[off];
                s[ct] = __builtin_amdgcn_mfma_f32_16x16x32_bf16(qf[ks], kf, s[ct], 0, 0, 0);
            }
        }

        // ---- online softmax (rows lk*4+r, reduce over 16-lane group) ----
        float corr[4];
        #pragma unroll
        for (int r = 0; r < 4; ++r) {
            float v = fmaxf(fmaxf(s[0][r], s[1][r]), fmaxf(s[2][r], s[3][r]));
            #pragma unroll
            for (int msk = 1; msk <= 8; msk <<= 1)
                v = fmaxf(v, __shfl_xor(v, msk, 64));
            const float mnew = fmaxf(m_r[r], v);
            corr[r] = __expf(m_r[r] - mnew);
            m_r[r] = mnew;
        }
        float rsum[4] = {0.f, 0.f, 0.f, 0.f};
        unsigned short pbf[4][4];
        #pragma unroll
        for (int ct = 0; ct < 4; ++ct) {
            #pragma unroll
            for (int r = 0; r < 4; ++r) {
                const float p = __expf(s[ct][r] - m_r[r]);
                rsum[r] += p;
                pbf[ct][r] = f2bf(p);
            }
        }
        #pragma unroll
        for (int r = 0; r < 4; ++r) {
            float v = rsum[r];
            #pragma unroll
            for (int msk = 1; msk <= 8; msk <<= 1)
                v += __shfl_xor(v, msk, 64);
            l_r[r] = l_r[r] * corr[r] + v;
        }
        #pragma unroll
        for (int dt = 0; dt < 4; ++dt) {
            #pragma unroll
            for (int r = 0; r < 4; ++r) o[dt][r] *= corr[r];
        }

        // ---- P -> LDS (per-wave region), bf16, swizzled ----
        #pragma unroll
        for (int ct = 0; ct < 4; ++ct) {
            const int key = ct * 16 + lq;
            #pragma unroll
            for (int r = 0; r < 4; ++r) {
                const int qrow = lk * 4 + r;
                const int off = (qrow * 128 + key * 2) ^ ((qrow & 7) << 4);
                *(unsigned short*)&Pw[off] = pbf[ct][r];
            }
        }
        // Intra-wave cross-lane LDS dependency (P write -> P read, no
        // barrier): force write completion + block scheduler hoisting.
        asm volatile("s_waitcnt lgkmcnt(0)" ::: "memory");
        __builtin_amdgcn_sched_barrier(0);

        // ---- O += P V ----
        #pragma unroll
        for (int ks = 0; ks < 2; ++ks) {
            const int offp = (lq * 128 + ks * 64 + lk * 16) ^ ((lq & 7) << 4);
            const bf16x8 pf = *(const bf16x8*)&Pw[offp];
            #pragma unroll
            for (int dt = 0; dt < 4; ++dt) {
                const int dh  = dt * 16 + lq;
                const int off = (dh * 128 + ks * 64 + lk * 16) ^ ((dh & 7) << 4);
                const bf16x8 vf = *(const bf16x8*)&Vts[off];
                o[dt] = __builtin_amdgcn_mfma_f32_16x16x32_bf16(pf, vf, o[dt], 0, 0, 0);
            }
        }
    }

    // ---- epilogue: O / l -> y (head-merged fp32) ----
    #pragma unroll
    for (int r = 0; r < 4; ++r) {
        const float inv = 1.0f / l_r[r];
        const int row = qt * 64 + w * 16 + lk * 4 + r;
        const size_t base = (size_t)(b * T + row) * D + h * DH;
        #pragma unroll
        for (int dt = 0; dt < 4; ++dt)
            y[base + dt * 16 + lq] = o[dt][r] * inv;
    }
}

// ---------------------------------------------------------------------------
extern "C" void kernel_launch(void* const* d_in, const int* in_sizes, int n_in,
                              void* d_out, int out_size, void* d_ws, size_t ws_size,
                              hipStream_t stream) {
    const float* x     = (const float*)d_in[0];
    const float* w_qkv = (const float*)d_in[1];
    const float* w_out = (const float*)d_in[2];
    float* out = (float*)d_out;

    float* qkv = (float*)d_ws;                    // (B*T, 3D)
    float* y   = qkv + (size_t)B * T * 3 * D;     // (B*T, D)

    gemm_f32<64, 64, 16><<<dim3((3 * D) / 64, (B * T) / 64), 256, 0, stream>>>(
        x, w_qkv, qkv, B * T, 3 * D, D);
    attn_mfma<<<dim3(T / 64, B * NH), 256, 0, stream>>>(qkv, y);
    gemm_f32<64, 64, 16><<<dim3(D / 64, (B * T) / 64), 256, 0, stream>>>(
        y, w_out, out, B * T, D, D);
}

// Round 4
// 486.726 us; speedup vs baseline: 6.3664x; 2.5263x over previous
//
#include <hip/hip_runtime.h>

#define B  4
#define T  2048
#define D  1024
#define NH 16
#define DH 64
#define MROWS (B*T)   // 8192

typedef __attribute__((ext_vector_type(8))) short bf16x8;
typedef __attribute__((ext_vector_type(4))) float f32x4;
typedef __attribute__((address_space(1))) const void gvoid;
typedef __attribute__((address_space(3))) void lvoid;

__device__ inline unsigned short f2bf(float f) {
    union { float f; unsigned int u; } v; v.f = f;
    unsigned int r = v.u + 0x7fff + ((v.u >> 16) & 1);   // RNE
    return (unsigned short)(r >> 16);
}
__device__ inline float bf2f(unsigned short u) {
    union { unsigned int u; float f; } v; v.u = ((unsigned int)u) << 16;
    return v.f;
}

// ---------------------------------------------------------------------------
// Split fp32 array into bf16 hi + bf16 lo (lo = bf16(x - hi)).
// ---------------------------------------------------------------------------
__global__ __launch_bounds__(256)
void split_f32(const float* __restrict__ in, unsigned short* __restrict__ hi,
               unsigned short* __restrict__ lo, int n4) {
    for (int i = blockIdx.x * 256 + threadIdx.x; i < n4; i += gridDim.x * 256) {
        const float4 v = ((const float4*)in)[i];
        ushort4 h, l;
        h.x = f2bf(v.x); l.x = f2bf(v.x - bf2f(h.x));
        h.y = f2bf(v.y); l.y = f2bf(v.y - bf2f(h.y));
        h.z = f2bf(v.z); l.z = f2bf(v.z - bf2f(h.z));
        h.w = f2bf(v.w); l.w = f2bf(v.w - bf2f(h.w));
        ((ushort4*)hi)[i] = h;
        ((ushort4*)lo)[i] = l;
    }
}

// ---------------------------------------------------------------------------
// Transpose (K x N fp32) -> (N x K) bf16 hi/lo, 32x32 LDS tiles.
// ---------------------------------------------------------------------------
__global__ __launch_bounds__(256)
void split_tr(const float* __restrict__ Wm, unsigned short* __restrict__ hi,
              unsigned short* __restrict__ lo, int K, int N) {
    __shared__ float Tl[32][36];
    const int nt = blockIdx.x * 32, kt = blockIdx.y * 32;
    const int t = threadIdx.x;
    {
        const int r = t >> 3, c = (t & 7) * 4;
        const float4 v = *(const float4*)&Wm[(size_t)(kt + r) * N + nt + c];
        Tl[r][c] = v.x; Tl[r][c + 1] = v.y; Tl[r][c + 2] = v.z; Tl[r][c + 3] = v.w;
    }
    __syncthreads();
    {
        const int nl = t >> 3, k4 = (t & 7) * 4;
        const float v0 = Tl[k4 + 0][nl], v1 = Tl[k4 + 1][nl];
        const float v2 = Tl[k4 + 2][nl], v3 = Tl[k4 + 3][nl];
        ushort4 h, l;
        h.x = f2bf(v0); l.x = f2bf(v0 - bf2f(h.x));
        h.y = f2bf(v1); l.y = f2bf(v1 - bf2f(h.y));
        h.z = f2bf(v2); l.z = f2bf(v2 - bf2f(h.z));
        h.w = f2bf(v3); l.w = f2bf(v3 - bf2f(h.w));
        const size_t o = (size_t)(nt + nl) * K + kt + k4;
        *(ushort4*)&hi[o] = h;
        *(ushort4*)&lo[o] = l;
    }
}

// ---------------------------------------------------------------------------
// Split-bf16 MFMA GEMM: C = A@B with A ~ Ahi+Alo (MxK), B^T given as
// Bt ~ Bthi+Btlo (NxK, row-major). 3 passes: hi*hi + hi*lo + lo*hi.
// 128x128 tile, 4 waves (64x64/wave), BK=32. LDS row = 128B: [hi 64B | lo 64B]
// XOR-swizzled by (row&7)<<4; staged via global_load_lds with pre-swizzled
// per-lane global source (linear LDS dest).
// ---------------------------------------------------------------------------
template<bool OUT_BF16>
__global__ __launch_bounds__(256)
void gemm_split(const unsigned short* __restrict__ Ahi, const unsigned short* __restrict__ Alo,
                const unsigned short* __restrict__ Bthi, const unsigned short* __restrict__ Btlo,
                void* __restrict__ Cout, int M, int N, int K) {
    __shared__ unsigned char As[128 * 128];
    __shared__ unsigned char Bs[128 * 128];
    const int tid  = threadIdx.x;
    const int w    = tid >> 6;
    const int lane = tid & 63;
    const int lq   = lane & 15;
    const int lk   = lane >> 4;
    const int bm = blockIdx.y * 128;
    const int bn = blockIdx.x * 128;

    // pre-swizzled staging source pattern: lane l -> LDS (row=l>>3, slot=l&7);
    // content must be chunk (slot ^ row) of that row (rows 8-aligned).
    const int srow   = lane >> 3;
    const int sidx   = (lane & 7) ^ srow;   // 0..7: 0-3 = hi chunks, 4-7 = lo
    const int shalf  = sidx >> 2;
    const int schunk = sidx & 3;
    const unsigned short* aPtr = (shalf ? Alo : Ahi) + (size_t)(bm + w * 32 + srow) * K + schunk * 8;
    const unsigned short* bPtr = (shalf ? Btlo : Bthi) + (size_t)(bn + w * 32 + srow) * K + schunk * 8;

    f32x4 acc[4][4];
    #pragma unroll
    for (int m = 0; m < 4; ++m)
        #pragma unroll
        for (int n = 0; n < 4; ++n) acc[m][n] = f32x4{0.f, 0.f, 0.f, 0.f};

    const int wr = (w >> 1) * 64, wc = (w & 1) * 64;

    for (int k0 = 0; k0 < K; k0 += 32) {
        __syncthreads();
        #pragma unroll
        for (int i = 0; i < 4; ++i) {
            const int r = w * 32 + i * 8;
            __builtin_amdgcn_global_load_lds((gvoid*)(aPtr + (size_t)i * 8 * K + k0),
                                             (lvoid*)&As[r * 128], 16, 0, 0);
            __builtin_amdgcn_global_load_lds((gvoid*)(bPtr + (size_t)i * 8 * K + k0),
                                             (lvoid*)&Bs[r * 128], 16, 0, 0);
        }
        __syncthreads();   // drains vmcnt + lgkm

        bf16x8 ah[4], al[4], bh[4], bl[4];
        #pragma unroll
        for (int m = 0; m < 4; ++m) {
            const int row = wr + m * 16 + lq;
            const int sw  = row & 7;
            ah[m] = *(const bf16x8*)&As[row * 128 + ((lk ^ sw) << 4)];
            al[m] = *(const bf16x8*)&As[row * 128 + (((4 + lk) ^ sw) << 4)];
        }
        #pragma unroll
        for (int n = 0; n < 4; ++n) {
            const int row = wc + n * 16 + lq;
            const int sw  = row & 7;
            bh[n] = *(const bf16x8*)&Bs[row * 128 + ((lk ^ sw) << 4)];
            bl[n] = *(const bf16x8*)&Bs[row * 128 + (((4 + lk) ^ sw) << 4)];
        }
        #pragma unroll
        for (int m = 0; m < 4; ++m)
            #pragma unroll
            for (int n = 0; n < 4; ++n) {
                acc[m][n] = __builtin_amdgcn_mfma_f32_16x16x32_bf16(ah[m], bh[n], acc[m][n], 0, 0, 0);
                acc[m][n] = __builtin_amdgcn_mfma_f32_16x16x32_bf16(ah[m], bl[n], acc[m][n], 0, 0, 0);
                acc[m][n] = __builtin_amdgcn_mfma_f32_16x16x32_bf16(al[m], bh[n], acc[m][n], 0, 0, 0);
            }
    }

    #pragma unroll
    for (int m = 0; m < 4; ++m)
        #pragma unroll
        for (int ri = 0; ri < 4; ++ri) {
            const int row = bm + wr + m * 16 + lk * 4 + ri;
            #pragma unroll
            for (int n = 0; n < 4; ++n) {
                const int col = bn + wc + n * 16 + lq;
                if (OUT_BF16)
                    ((unsigned short*)Cout)[(size_t)row * N + col] = f2bf(acc[m][n][ri]);
                else
                    ((float*)Cout)[(size_t)row * N + col] = acc[m][n][ri];
            }
        }
}

// ---------------------------------------------------------------------------
// bf16-MFMA flash attention. qkv (B*T, 3D) bf16: per row [q|k|v].
// Block = 256 thr (4 waves), Q-tile 64 (16/wave), KV-tile 64. Logits scaled
// post-MFMA. Output: y hi/lo bf16 (head-merged) for the split out-proj GEMM.
// ---------------------------------------------------------------------------
__global__ __launch_bounds__(256)
void attn_mfma(const unsigned short* __restrict__ qkv,
               unsigned short* __restrict__ yhi, unsigned short* __restrict__ ylo) {
    const int bh  = blockIdx.y;
    const int b   = bh / NH;
    const int h   = bh % NH;
    const int qt  = blockIdx.x;
    const int tid = threadIdx.x;
    const int w    = tid >> 6;
    const int lane = tid & 63;
    const int lq   = lane & 15;
    const int lk   = lane >> 4;

    __shared__ unsigned char Ks [64 * 128];  // bf16 [key][dh], swizzled
    __shared__ unsigned char Vts[64 * 128];  // bf16 [dh][key], swizzled
    __shared__ unsigned char QPs[64 * 128];  // Q tile, then per-wave P

    // ---- stage Q (bf16 copy, swizzled) ----
    #pragma unroll
    for (int it = 0; it < 2; ++it) {
        const int c   = tid + 256 * it;      // 0..511 chunks of 16B
        const int row = c >> 3, slot = c & 7;
        const bf16x8 v = *(const bf16x8*)&qkv[(size_t)(b * T + qt * 64 + row) * (3 * D) + h * DH + slot * 8];
        *(bf16x8*)&QPs[row * 128 + ((slot ^ (row & 7)) << 4)] = v;
    }
    __syncthreads();

    bf16x8 qf[2];
    #pragma unroll
    for (int ks = 0; ks < 2; ++ks) {
        const int row = w * 16 + lq;
        qf[ks] = *(const bf16x8*)&QPs[row * 128 + (((ks * 4 + lk) ^ (row & 7)) << 4)];
    }

    f32x4 o[4];
    #pragma unroll
    for (int dt = 0; dt < 4; ++dt) o[dt] = f32x4{0.f, 0.f, 0.f, 0.f};
    float m_r[4] = {-1e30f, -1e30f, -1e30f, -1e30f};
    float l_r[4] = {0.f, 0.f, 0.f, 0.f};

    unsigned char* Pw = &QPs[w * 2048];

    // per-lane pre-swizzled source for K gload_lds
    const int srow   = lane >> 3;
    const int schunk = (lane & 7) ^ srow;
    const unsigned short* kBase = qkv + (size_t)(b * T + srow) * (3 * D) + D + h * DH + schunk * 8;

    for (int kt = 0; kt < T; kt += 64) {
        __syncthreads();
        // ---- K tile via global_load_lds (2 insts/wave, 8 rows each) ----
        #pragma unroll
        for (int i = 0; i < 2; ++i) {
            const int r0 = w * 16 + i * 8;
            __builtin_amdgcn_global_load_lds((gvoid*)(kBase + (size_t)(kt + r0) * (3 * D)),
                                             (lvoid*)&Ks[r0 * 128], 16, 0, 0);
        }
        // ---- V transposed (reg-staged bf16 copy) ----
        {
            const int key = tid & 63;
            const int dh0 = (tid >> 6) * 16;
            const unsigned short* vsrc = &qkv[(size_t)(b * T + kt + key) * (3 * D) + 2 * D + h * DH + dh0];
            const bf16x8 v0 = *(const bf16x8*)&vsrc[0];
            const bf16x8 v1 = *(const bf16x8*)&vsrc[8];
            #pragma unroll
            for (int j = 0; j < 8; ++j) {
                const int d0 = dh0 + j, d1 = dh0 + 8 + j;
                *(unsigned short*)&Vts[(d0 * 128 + key * 2) ^ ((d0 & 7) << 4)] = (unsigned short)v0[j];
                *(unsigned short*)&Vts[(d1 * 128 + key * 2) ^ ((d1 & 7) << 4)] = (unsigned short)v1[j];
            }
        }
        __syncthreads();

        // ---- S = Q K^T ----
        f32x4 s[4];
        #pragma unroll
        for (int ct = 0; ct < 4; ++ct) s[ct] = f32x4{0.f, 0.f, 0.f, 0.f};
        #pragma unroll
        for (int ks = 0; ks < 2; ++ks) {
            #pragma unroll
            for (int ct = 0; ct < 4; ++ct) {
                const int key = ct * 16 + lq;
                const bf16x8 kf = *(const bf16x8*)&Ks[key * 128 + (((ks * 4 + lk) ^ (key & 7)) << 4)];
                s[ct] = __builtin_amdgcn_mfma_f32_16x16x32_bf16(qf[ks], kf, s[ct], 0, 0, 0);
            }
        }
        #pragma unroll
        for (int ct = 0; ct < 4; ++ct)
            #pragma unroll
            for (int r = 0; r < 4; ++r) s[ct][r] *= 0.125f;   // 1/sqrt(DH)

        // ---- online softmax ----
        float corr[4];
        #pragma unroll
        for (int r = 0; r < 4; ++r) {
            float v = fmaxf(fmaxf(s[0][r], s[1][r]), fmaxf(s[2][r], s[3][r]));
            #pragma unroll
            for (int msk = 1; msk <= 8; msk <<= 1)
                v = fmaxf(v, __shfl_xor(v, msk, 64));
            const float mnew = fmaxf(m_r[r], v);
            corr[r] = __expf(m_r[r] - mnew);
            m_r[r] = mnew;
        }
        float rsum[4] = {0.f, 0.f, 0.f, 0.f};
        unsigned short pbf[4][4];
        #pragma unroll
        for (int ct = 0; ct < 4; ++ct)
            #pragma unroll
            for (int r = 0; r < 4; ++r) {
                const float p = __expf(s[ct][r] - m_r[r]);
                rsum[r] += p;
                pbf[ct][r] = f2bf(p);
            }
        #pragma unroll
        for (int r = 0; r < 4; ++r) {
            float v = rsum[r];
            #pragma unroll
            for (int msk = 1; msk <= 8; msk <<= 1)
                v += __shfl_xor(v, msk, 64);
            l_r[r] = l_r[r] * corr[r] + v;
        }
        #pragma unroll
        for (int dt = 0; dt < 4; ++dt)
            #pragma unroll
            for (int r = 0; r < 4; ++r) o[dt][r] *= corr[r];

        // ---- P -> per-wave LDS ----
        #pragma unroll
        for (int ct = 0; ct < 4; ++ct) {
            const int key = ct * 16 + lq;
            #pragma unroll
            for (int r = 0; r < 4; ++r) {
                const int qrow = lk * 4 + r;
                *(unsigned short*)&Pw[(qrow * 128 + key * 2) ^ ((qrow & 7) << 4)] = pbf[ct][r];
            }
        }
        asm volatile("s_waitcnt lgkmcnt(0)" ::: "memory");
        __builtin_amdgcn_sched_barrier(0);

        // ---- O += P V ----
        #pragma unroll
        for (int ks = 0; ks < 2; ++ks) {
            const bf16x8 pf = *(const bf16x8*)&Pw[(lq * 128 + ks * 64 + lk * 16) ^ ((lq & 7) << 4)];
            #pragma unroll
            for (int dt = 0; dt < 4; ++dt) {
                const int dh = dt * 16 + lq;
                const bf16x8 vf = *(const bf16x8*)&Vts[(dh * 128 + ks * 64 + lk * 16) ^ ((dh & 7) << 4)];
                o[dt] = __builtin_amdgcn_mfma_f32_16x16x32_bf16(pf, vf, o[dt], 0, 0, 0);
            }
        }
    }

    // ---- epilogue: O/l -> y hi/lo bf16 ----
    #pragma unroll
    for (int r = 0; r < 4; ++r) {
        const float inv = 1.0f / l_r[r];
        const int row = qt * 64 + w * 16 + lk * 4 + r;
        const size_t base = (size_t)(b * T + row) * D + h * DH;
        #pragma unroll
        for (int dt = 0; dt < 4; ++dt) {
            const float val = o[dt][r] * inv;
            const unsigned short hv = f2bf(val);
            yhi[base + dt * 16 + lq] = hv;
            ylo[base + dt * 16 + lq] = f2bf(val - bf2f(hv));
        }
    }
}

// ---------------------------------------------------------------------------
extern "C" void kernel_launch(void* const* d_in, const int* in_sizes, int n_in,
                              void* d_out, int out_size, void* d_ws, size_t ws_size,
                              hipStream_t stream) {
    const float* x     = (const float*)d_in[0];
    const float* w_qkv = (const float*)d_in[1];
    const float* w_out = (const float*)d_in[2];

    // workspace layout (ushorts), ~101 MB total
    unsigned short* Xhi = (unsigned short*)d_ws;              // M*D   (reused as Yhi)
    unsigned short* Xlo = Xhi + (size_t)MROWS * D;            // M*D   (reused as Ylo)
    unsigned short* Wqh = Xlo + (size_t)MROWS * D;            // 3D*D (N x K)
    unsigned short* Wql = Wqh + (size_t)3 * D * D;
    unsigned short* Woh = Wql + (size_t)3 * D * D;            // D*D
    unsigned short* Wol = Woh + (size_t)D * D;
    unsigned short* QKV = Wol + (size_t)D * D;                // M*3D bf16

    split_f32<<<2048, 256, 0, stream>>>(x, Xhi, Xlo, MROWS * D / 4);
    split_tr<<<dim3(3 * D / 32, D / 32), 256, 0, stream>>>(w_qkv, Wqh, Wql, D, 3 * D);
    split_tr<<<dim3(D / 32, D / 32), 256, 0, stream>>>(w_out, Woh, Wol, D, D);

    gemm_split<true><<<dim3(3 * D / 128, MROWS / 128), 256, 0, stream>>>(
        Xhi, Xlo, Wqh, Wql, QKV, MROWS, 3 * D, D);

    attn_mfma<<<dim3(T / 64, B * NH), 256, 0, stream>>>(QKV, Xhi, Xlo);

    gemm_split<false><<<dim3(D / 128, MROWS / 128), 256, 0, stream>>>(
        Xhi, Xlo, Woh, Wol, d_out, MROWS, D, D);
}

// Round 6
// 402.953 us; speedup vs baseline: 7.6899x; 1.2079x over previous
//
#include <hip/hip_runtime.h>

#define B  4
#define T  2048
#define D  1024
#define NH 16
#define DH 64
#define MROWS (B*T)   // 8192

typedef __attribute__((ext_vector_type(8))) short bf16x8;
typedef __attribute__((ext_vector_type(4))) float f32x4;
typedef __attribute__((ext_vector_type(4))) unsigned short u16x4;
typedef __attribute__((address_space(1))) const void gvoid;
typedef __attribute__((address_space(3))) void lvoid;

#define C_EXP 0.18033688011112042f   // 0.125 * log2(e)

__device__ inline unsigned short f2bf(float f) {
    union { float f; unsigned int u; } v; v.f = f;
    unsigned int r = v.u + 0x7fff + ((v.u >> 16) & 1);   // RNE
    return (unsigned short)(r >> 16);
}
__device__ inline float bf2f(unsigned short u) {
    union { unsigned int u; float f; } v; v.u = ((unsigned int)u) << 16;
    return v.f;
}
__device__ inline float exp2_fast(float x) {
    float r;
    asm("v_exp_f32 %0, %1" : "=v"(r) : "v"(x));   // D = 2^S0
    return r;
}

// ---------------------------------------------------------------------------
// Split fp32 array into bf16 hi + bf16 lo (lo = bf16(x - hi)).
// ---------------------------------------------------------------------------
__global__ __launch_bounds__(256)
void split_f32(const float* __restrict__ in, unsigned short* __restrict__ hi,
               unsigned short* __restrict__ lo, int n4) {
    for (int i = blockIdx.x * 256 + threadIdx.x; i < n4; i += gridDim.x * 256) {
        const float4 v = ((const float4*)in)[i];
        ushort4 h, l;
        h.x = f2bf(v.x); l.x = f2bf(v.x - bf2f(h.x));
        h.y = f2bf(v.y); l.y = f2bf(v.y - bf2f(h.y));
        h.z = f2bf(v.z); l.z = f2bf(v.z - bf2f(h.z));
        h.w = f2bf(v.w); l.w = f2bf(v.w - bf2f(h.w));
        ((ushort4*)hi)[i] = h;
        ((ushort4*)lo)[i] = l;
    }
}

// ---------------------------------------------------------------------------
// Transpose (K x N fp32) -> (N x K) bf16 hi/lo, 32x32 LDS tiles.
// ---------------------------------------------------------------------------
__global__ __launch_bounds__(256)
void split_tr(const float* __restrict__ Wm, unsigned short* __restrict__ hi,
              unsigned short* __restrict__ lo, int K, int N) {
    __shared__ float Tl[32][36];
    const int nt = blockIdx.x * 32, kt = blockIdx.y * 32;
    const int t = threadIdx.x;
    {
        const int r = t >> 3, c = (t & 7) * 4;
        const float4 v = *(const float4*)&Wm[(size_t)(kt + r) * N + nt + c];
        Tl[r][c] = v.x; Tl[r][c + 1] = v.y; Tl[r][c + 2] = v.z; Tl[r][c + 3] = v.w;
    }
    __syncthreads();
    {
        const int nl = t >> 3, k4 = (t & 7) * 4;
        const float v0 = Tl[k4 + 0][nl], v1 = Tl[k4 + 1][nl];
        const float v2 = Tl[k4 + 2][nl], v3 = Tl[k4 + 3][nl];
        ushort4 h, l;
        h.x = f2bf(v0); l.x = f2bf(v0 - bf2f(h.x));
        h.y = f2bf(v1); l.y = f2bf(v1 - bf2f(h.y));
        h.z = f2bf(v2); l.z = f2bf(v2 - bf2f(h.z));
        h.w = f2bf(v3); l.w = f2bf(v3 - bf2f(h.w));
        const size_t o = (size_t)(nt + nl) * K + kt + k4;
        *(ushort4*)&hi[o] = h;
        *(ushort4*)&lo[o] = l;
    }
}

// ---------------------------------------------------------------------------
// Split-bf16 MFMA GEMM (unchanged from round 4): C = A@B, 3 MFMA passes.
// ---------------------------------------------------------------------------
template<bool OUT_BF16>
__global__ __launch_bounds__(256)
void gemm_split(const unsigned short* __restrict__ Ahi, const unsigned short* __restrict__ Alo,
                const unsigned short* __restrict__ Bthi, const unsigned short* __restrict__ Btlo,
                void* __restrict__ Cout, int M, int N, int K) {
    __shared__ unsigned char As[128 * 128];
    __shared__ unsigned char Bs[128 * 128];
    const int tid  = threadIdx.x;
    const int w    = tid >> 6;
    const int lane = tid & 63;
    const int lq   = lane & 15;
    const int lk   = lane >> 4;
    const int bm = blockIdx.y * 128;
    const int bn = blockIdx.x * 128;

    const int srow   = lane >> 3;
    const int sidx   = (lane & 7) ^ srow;
    const int shalf  = sidx >> 2;
    const int schunk = sidx & 3;
    const unsigned short* aPtr = (shalf ? Alo : Ahi) + (size_t)(bm + w * 32 + srow) * K + schunk * 8;
    const unsigned short* bPtr = (shalf ? Btlo : Bthi) + (size_t)(bn + w * 32 + srow) * K + schunk * 8;

    f32x4 acc[4][4];
    #pragma unroll
    for (int m = 0; m < 4; ++m)
        #pragma unroll
        for (int n = 0; n < 4; ++n) acc[m][n] = f32x4{0.f, 0.f, 0.f, 0.f};

    const int wr = (w >> 1) * 64, wc = (w & 1) * 64;

    for (int k0 = 0; k0 < K; k0 += 32) {
        __syncthreads();
        #pragma unroll
        for (int i = 0; i < 4; ++i) {
            const int r = w * 32 + i * 8;
            __builtin_amdgcn_global_load_lds((gvoid*)(aPtr + (size_t)i * 8 * K + k0),
                                             (lvoid*)&As[r * 128], 16, 0, 0);
            __builtin_amdgcn_global_load_lds((gvoid*)(bPtr + (size_t)i * 8 * K + k0),
                                             (lvoid*)&Bs[r * 128], 16, 0, 0);
        }
        __syncthreads();

        bf16x8 ah[4], al[4], bh[4], bl[4];
        #pragma unroll
        for (int m = 0; m < 4; ++m) {
            const int row = wr + m * 16 + lq;
            const int sw  = row & 7;
            ah[m] = *(const bf16x8*)&As[row * 128 + ((lk ^ sw) << 4)];
            al[m] = *(const bf16x8*)&As[row * 128 + (((4 + lk) ^ sw) << 4)];
        }
        #pragma unroll
        for (int n = 0; n < 4; ++n) {
            const int row = wc + n * 16 + lq;
            const int sw  = row & 7;
            bh[n] = *(const bf16x8*)&Bs[row * 128 + ((lk ^ sw) << 4)];
            bl[n] = *(const bf16x8*)&Bs[row * 128 + (((4 + lk) ^ sw) << 4)];
        }
        #pragma unroll
        for (int m = 0; m < 4; ++m)
            #pragma unroll
            for (int n = 0; n < 4; ++n) {
                acc[m][n] = __builtin_amdgcn_mfma_f32_16x16x32_bf16(ah[m], bh[n], acc[m][n], 0, 0, 0);
                acc[m][n] = __builtin_amdgcn_mfma_f32_16x16x32_bf16(ah[m], bl[n], acc[m][n], 0, 0, 0);
                acc[m][n] = __builtin_amdgcn_mfma_f32_16x16x32_bf16(al[m], bh[n], acc[m][n], 0, 0, 0);
            }
    }

    #pragma unroll
    for (int m = 0; m < 4; ++m)
        #pragma unroll
        for (int ri = 0; ri < 4; ++ri) {
            const int row = bm + wr + m * 16 + lk * 4 + ri;
            #pragma unroll
            for (int n = 0; n < 4; ++n) {
                const int col = bn + wc + n * 16 + lq;
                if (OUT_BF16)
                    ((unsigned short*)Cout)[(size_t)row * N + col] = f2bf(acc[m][n][ri]);
                else
                    ((float*)Cout)[(size_t)row * N + col] = acc[m][n][ri];
            }
        }
}

// ---------------------------------------------------------------------------
// bf16-MFMA flash attention, swapped-QK^T + single-barrier double-buffered.
// qkv (B*T, 3D) bf16. 4 waves, Q-tile 64 (16/wave), KV-tile 64.
// Softmax in raw-logit domain: p = exp2((s - m) * 0.125*log2e).
// Stat layout: lane owns query lq (replicated over lk); O layout rows lk*4+r.
// ---------------------------------------------------------------------------
__global__ __launch_bounds__(256)
void attn_mfma(const unsigned short* __restrict__ qkv,
               unsigned short* __restrict__ yhi, unsigned short* __restrict__ ylo) {
    const int bh  = blockIdx.y;
    const int b   = bh / NH;
    const int h   = bh % NH;
    const int qt  = blockIdx.x;
    const int tid = threadIdx.x;
    const int w    = tid >> 6;
    const int lane = tid & 63;
    const int lq   = lane & 15;
    const int lk   = lane >> 4;

    __shared__ unsigned char Ks [2][64 * 128];  // bf16 [key][dh], swizzled, dbuf
    __shared__ unsigned char Vts[2][64 * 128];  // bf16 [dh][key], swizzled, dbuf
    __shared__ unsigned char QPs[64 * 128];     // Q tile; reused as per-wave P

    // ---- stage Q (bf16 copy, swizzled) ----
    #pragma unroll
    for (int it = 0; it < 2; ++it) {
        const int c   = tid + 256 * it;
        const int row = c >> 3, slot = c & 7;
        const bf16x8 v = *(const bf16x8*)&qkv[(size_t)(b * T + qt * 64 + row) * (3 * D) + h * DH + slot * 8];
        *(bf16x8*)&QPs[row * 128 + ((slot ^ (row & 7)) << 4)] = v;
    }

    // per-lane pre-swizzled source for K global_load_lds
    const int srow   = lane >> 3;
    const int schunk = (lane & 7) ^ srow;
    const unsigned short* kBase = qkv + (size_t)(b * T + srow) * (3 * D) + D + h * DH + schunk * 8;
    // V staging source: thread covers keys w*16+lk*4+i (i=0..3), dh lq*4..lq*4+3
    const unsigned short* vBase = qkv + (size_t)(b * T + w * 16 + lk * 4) * (3 * D) + 2 * D + h * DH + lq * 4;

    // ---- prologue: stage tile 0 into buffer 0 ----
    #pragma unroll
    for (int i = 0; i < 2; ++i) {
        const int r0 = w * 16 + i * 8;
        __builtin_amdgcn_global_load_lds((gvoid*)(kBase + (size_t)r0 * (3 * D)),
                                         (lvoid*)&Ks[0][r0 * 128], 16, 0, 0);
    }
    u16x4 vr[4];
    #pragma unroll
    for (int i = 0; i < 4; ++i)
        vr[i] = *(const u16x4*)(vBase + (size_t)i * (3 * D));
    #pragma unroll
    for (int j = 0; j < 4; ++j) {
        const int dh = lq * 4 + j;
        uint2 pk2;
        pk2.x = (unsigned int)vr[0][j] | ((unsigned int)vr[1][j] << 16);
        pk2.y = (unsigned int)vr[2][j] | ((unsigned int)vr[3][j] << 16);
        *(uint2*)&Vts[0][(dh * 128 + w * 32 + lk * 8) ^ ((dh & 7) << 4)] = pk2;
    }
    __syncthreads();

    // ---- Q fragments (wave w reads only its own rows w*16..w*16+15) ----
    bf16x8 qf[2];
    #pragma unroll
    for (int ks = 0; ks < 2; ++ks) {
        const int row = w * 16 + lq;
        qf[ks] = *(const bf16x8*)&QPs[row * 128 + (((ks * 4 + lk) ^ (row & 7)) << 4)];
    }

    f32x4 o[4];
    #pragma unroll
    for (int dt = 0; dt < 4; ++dt) o[dt] = f32x4{0.f, 0.f, 0.f, 0.f};
    float m_r = -1e30f, l_r = 0.f;

    unsigned char* Pw = &QPs[w * 2048];

    for (int t = 0; t < T / 64; ++t) {
        const int c = t & 1;
        const bool more = (t + 1 < T / 64);
        // ---- issue next-tile staging early (hides under compute) ----
        if (more) {
            const int ktn = (t + 1) * 64;
            #pragma unroll
            for (int i = 0; i < 2; ++i) {
                const int r0 = w * 16 + i * 8;
                __builtin_amdgcn_global_load_lds((gvoid*)(kBase + (size_t)(ktn + r0) * (3 * D)),
                                                 (lvoid*)&Ks[c ^ 1][r0 * 128], 16, 0, 0);
            }
            #pragma unroll
            for (int i = 0; i < 4; ++i)
                vr[i] = *(const u16x4*)(vBase + (size_t)(ktn + i) * (3 * D));
        }

        // ---- S^T = K Q (swapped): lane owns 16 logits of query lq ----
        f32x4 s[4];
        #pragma unroll
        for (int ct = 0; ct < 4; ++ct) s[ct] = f32x4{0.f, 0.f, 0.f, 0.f};
        __builtin_amdgcn_s_setprio(1);
        #pragma unroll
        for (int ks = 0; ks < 2; ++ks) {
            #pragma unroll
            for (int ct = 0; ct < 4; ++ct) {
                const int key = ct * 16 + lq;
                const bf16x8 kf = *(const bf16x8*)&Ks[c][key * 128 + (((ks * 4 + lk) ^ (key & 7)) << 4)];
                s[ct] = __builtin_amdgcn_mfma_f32_16x16x32_bf16(kf, qf[ks], s[ct], 0, 0, 0);
            }
        }
        __builtin_amdgcn_s_setprio(0);

        // ---- online softmax (raw-logit domain) ----
        float v16 = s[0][0];
        #pragma unroll
        for (int ct = 0; ct < 4; ++ct)
            #pragma unroll
            for (int r = 0; r < 4; ++r) v16 = fmaxf(v16, s[ct][r]);
        v16 = fmaxf(v16, __shfl_xor(v16, 16));
        v16 = fmaxf(v16, __shfl_xor(v16, 32));
        if (__any(v16 > m_r)) {
            const float mnew = fmaxf(m_r, v16);
            const float corr = exp2_fast((m_r - mnew) * C_EXP);
            m_r = mnew;
            l_r *= corr;
            float corrO[4];
            #pragma unroll
            for (int r = 0; r < 4; ++r) corrO[r] = __shfl(corr, lk * 4 + r);
            #pragma unroll
            for (int dt = 0; dt < 4; ++dt)
                #pragma unroll
                for (int r = 0; r < 4; ++r) o[dt][r] *= corrO[r];
        }
        const float mC = m_r * C_EXP;
        float p[4][4];
        float tsum = 0.f;
        #pragma unroll
        for (int ct = 0; ct < 4; ++ct)
            #pragma unroll
            for (int r = 0; r < 4; ++r) {
                p[ct][r] = exp2_fast(__builtin_fmaf(s[ct][r], C_EXP, -mC));
                tsum += p[ct][r];
            }
        tsum += __shfl_xor(tsum, 16);
        tsum += __shfl_xor(tsum, 32);
        l_r += tsum;

        // ---- P pack (v_cvt_pk_bf16_f32) + 4x ds_write_b64 ----
        #pragma unroll
        for (int ct = 0; ct < 4; ++ct) {
            uint2 pk2;
            asm("v_cvt_pk_bf16_f32 %0, %1, %2" : "=v"(pk2.x) : "v"(p[ct][0]), "v"(p[ct][1]));
            asm("v_cvt_pk_bf16_f32 %0, %1, %2" : "=v"(pk2.y) : "v"(p[ct][2]), "v"(p[ct][3]));
            *(uint2*)&Pw[(lq * 128 + ct * 32 + lk * 8) ^ ((lq & 7) << 4)] = pk2;
        }
        asm volatile("s_waitcnt lgkmcnt(0)" ::: "memory");
        __builtin_amdgcn_sched_barrier(0);

        // ---- O += P V ----
        __builtin_amdgcn_s_setprio(1);
        #pragma unroll
        for (int ks = 0; ks < 2; ++ks) {
            const bf16x8 pf = *(const bf16x8*)&Pw[(lq * 128 + ks * 64 + lk * 16) ^ ((lq & 7) << 4)];
            #pragma unroll
            for (int dt = 0; dt < 4; ++dt) {
                const int dh = dt * 16 + lq;
                const bf16x8 vf = *(const bf16x8*)&Vts[c][(dh * 128 + ks * 64 + lk * 16) ^ ((dh & 7) << 4)];
                o[dt] = __builtin_amdgcn_mfma_f32_16x16x32_bf16(pf, vf, o[dt], 0, 0, 0);
            }
        }
        __builtin_amdgcn_s_setprio(0);

        // ---- write next V tile into other buffer (vmcnt auto-waited) ----
        if (more) {
            #pragma unroll
            for (int j = 0; j < 4; ++j) {
                const int dh = lq * 4 + j;
                uint2 pk2;
                pk2.x = (unsigned int)vr[0][j] | ((unsigned int)vr[1][j] << 16);
                pk2.y = (unsigned int)vr[2][j] | ((unsigned int)vr[3][j] << 16);
                *(uint2*)&Vts[c ^ 1][(dh * 128 + w * 32 + lk * 8) ^ ((dh & 7) << 4)] = pk2;
            }
        }
        __syncthreads();   // one barrier per tile
    }

    // ---- epilogue: O/l -> y hi/lo bf16 ----
    const float inv = 1.0f / l_r;
    float invO[4];
    #pragma unroll
    for (int r = 0; r < 4; ++r) invO[r] = __shfl(inv, lk * 4 + r);
    #pragma unroll
    for (int r = 0; r < 4; ++r) {
        const int row = qt * 64 + w * 16 + lk * 4 + r;
        const size_t base = (size_t)(b * T + row) * D + h * DH;
        #pragma unroll
        for (int dt = 0; dt < 4; ++dt) {
            const float val = o[dt][r] * invO[r];
            const unsigned short hv = f2bf(val);
            yhi[base + dt * 16 + lq] = hv;
            ylo[base + dt * 16 + lq] = f2bf(val - bf2f(hv));
        }
    }
}

// ---------------------------------------------------------------------------
extern "C" void kernel_launch(void* const* d_in, const int* in_sizes, int n_in,
                              void* d_out, int out_size, void* d_ws, size_t ws_size,
                              hipStream_t stream) {
    const float* x     = (const float*)d_in[0];
    const float* w_qkv = (const float*)d_in[1];
    const float* w_out = (const float*)d_in[2];

    unsigned short* Xhi = (unsigned short*)d_ws;              // M*D (reused as Yhi)
    unsigned short* Xlo = Xhi + (size_t)MROWS * D;            // M*D (reused as Ylo)
    unsigned short* Wqh = Xlo + (size_t)MROWS * D;            // 3D*D (N x K)
    unsigned short* Wql = Wqh + (size_t)3 * D * D;
    unsigned short* Woh = Wql + (size_t)3 * D * D;            // D*D
    unsigned short* Wol = Woh + (size_t)D * D;
    unsigned short* QKV = Wol + (size_t)D * D;                // M*3D bf16

    split_f32<<<2048, 256, 0, stream>>>(x, Xhi, Xlo, MROWS * D / 4);
    split_tr<<<dim3(3 * D / 32, D / 32), 256, 0, stream>>>(w_qkv, Wqh, Wql, D, 3 * D);
    split_tr<<<dim3(D / 32, D / 32), 256, 0, stream>>>(w_out, Woh, Wol, D, D);

    gemm_split<true><<<dim3(3 * D / 128, MROWS / 128), 256, 0, stream>>>(
        Xhi, Xlo, Wqh, Wql, QKV, MROWS, 3 * D, D);

    attn_mfma<<<dim3(T / 64, B * NH), 256, 0, stream>>>(QKV, Xhi, Xlo);

    gemm_split<false><<<dim3(D / 128, MROWS / 128), 256, 0, stream>>>(
        Xhi, Xlo, Woh, Wol, d_out, MROWS, D, D);
}

// Round 8
// 366.853 us; speedup vs baseline: 8.4466x; 1.0984x over previous
//
#include <hip/hip_runtime.h>

#define B  4
#define T  2048
#define D  1024
#define NH 16
#define DH 64
#define MROWS (B*T)   // 8192

typedef __attribute__((ext_vector_type(8))) short bf16x8;
typedef __attribute__((ext_vector_type(4))) float f32x4;
typedef __attribute__((ext_vector_type(4))) unsigned short u16x4;
typedef __attribute__((address_space(1))) const void gvoid;
typedef __attribute__((address_space(3))) void lvoid;

#define C_EXP 0.18033688011112042f   // 0.125 * log2(e)
// V-tile swizzle: must spread when dh = 4*lq+j (write) AND dh = dt*16+lq (read)
#define VSWZ(dh) (((((dh) ^ ((dh) >> 2)) & 7)) << 4)

__device__ inline unsigned short f2bf(float f) {
    union { float f; unsigned int u; } v; v.f = f;
    unsigned int r = v.u + 0x7fff + ((v.u >> 16) & 1);   // RNE
    return (unsigned short)(r >> 16);
}
__device__ inline float bf2f(unsigned short u) {
    union { unsigned int u; float f; } v; v.u = ((unsigned int)u) << 16;
    return v.f;
}
__device__ inline float exp2_fast(float x) {
    float r;
    asm("v_exp_f32 %0, %1" : "=v"(r) : "v"(x));   // D = 2^S0
    return r;
}

// ---------------------------------------------------------------------------
// Split fp32 array into bf16 hi + bf16 lo (lo = bf16(x - hi)).
// ---------------------------------------------------------------------------
__global__ __launch_bounds__(256)
void split_f32(const float* __restrict__ in, unsigned short* __restrict__ hi,
               unsigned short* __restrict__ lo, int n4) {
    for (int i = blockIdx.x * 256 + threadIdx.x; i < n4; i += gridDim.x * 256) {
        const float4 v = ((const float4*)in)[i];
        ushort4 h, l;
        h.x = f2bf(v.x); l.x = f2bf(v.x - bf2f(h.x));
        h.y = f2bf(v.y); l.y = f2bf(v.y - bf2f(h.y));
        h.z = f2bf(v.z); l.z = f2bf(v.z - bf2f(h.z));
        h.w = f2bf(v.w); l.w = f2bf(v.w - bf2f(h.w));
        ((ushort4*)hi)[i] = h;
        ((ushort4*)lo)[i] = l;
    }
}

// ---------------------------------------------------------------------------
// Transpose (K x N fp32) -> (N x K) bf16 hi/lo, 32x32 LDS tiles.
// ---------------------------------------------------------------------------
__global__ __launch_bounds__(256)
void split_tr(const float* __restrict__ Wm, unsigned short* __restrict__ hi,
              unsigned short* __restrict__ lo, int K, int N) {
    __shared__ float Tl[32][36];
    const int nt = blockIdx.x * 32, kt = blockIdx.y * 32;
    const int t = threadIdx.x;
    {
        const int r = t >> 3, c = (t & 7) * 4;
        const float4 v = *(const float4*)&Wm[(size_t)(kt + r) * N + nt + c];
        Tl[r][c] = v.x; Tl[r][c + 1] = v.y; Tl[r][c + 2] = v.z; Tl[r][c + 3] = v.w;
    }
    __syncthreads();
    {
        const int nl = t >> 3, k4 = (t & 7) * 4;
        const float v0 = Tl[k4 + 0][nl], v1 = Tl[k4 + 1][nl];
        const float v2 = Tl[k4 + 2][nl], v3 = Tl[k4 + 3][nl];
        ushort4 h, l;
        h.x = f2bf(v0); l.x = f2bf(v0 - bf2f(h.x));
        h.y = f2bf(v1); l.y = f2bf(v1 - bf2f(h.y));
        h.z = f2bf(v2); l.z = f2bf(v2 - bf2f(h.z));
        h.w = f2bf(v3); l.w = f2bf(v3 - bf2f(h.w));
        const size_t o = (size_t)(nt + nl) * K + kt + k4;
        *(ushort4*)&hi[o] = h;
        *(ushort4*)&lo[o] = l;
    }
}

// ---------------------------------------------------------------------------
// Split-bf16 MFMA GEMM (unchanged): C = A@B, 3 MFMA passes.
// ---------------------------------------------------------------------------
template<bool OUT_BF16>
__global__ __launch_bounds__(256)
void gemm_split(const unsigned short* __restrict__ Ahi, const unsigned short* __restrict__ Alo,
                const unsigned short* __restrict__ Bthi, const unsigned short* __restrict__ Btlo,
                void* __restrict__ Cout, int M, int N, int K) {
    __shared__ unsigned char As[128 * 128];
    __shared__ unsigned char Bs[128 * 128];
    const int tid  = threadIdx.x;
    const int w    = tid >> 6;
    const int lane = tid & 63;
    const int lq   = lane & 15;
    const int lk   = lane >> 4;
    const int bm = blockIdx.y * 128;
    const int bn = blockIdx.x * 128;

    const int srow   = lane >> 3;
    const int sidx   = (lane & 7) ^ srow;
    const int shalf  = sidx >> 2;
    const int schunk = sidx & 3;
    const unsigned short* aPtr = (shalf ? Alo : Ahi) + (size_t)(bm + w * 32 + srow) * K + schunk * 8;
    const unsigned short* bPtr = (shalf ? Btlo : Bthi) + (size_t)(bn + w * 32 + srow) * K + schunk * 8;

    f32x4 acc[4][4];
    #pragma unroll
    for (int m = 0; m < 4; ++m)
        #pragma unroll
        for (int n = 0; n < 4; ++n) acc[m][n] = f32x4{0.f, 0.f, 0.f, 0.f};

    const int wr = (w >> 1) * 64, wc = (w & 1) * 64;

    for (int k0 = 0; k0 < K; k0 += 32) {
        __syncthreads();
        #pragma unroll
        for (int i = 0; i < 4; ++i) {
            const int r = w * 32 + i * 8;
            __builtin_amdgcn_global_load_lds((gvoid*)(aPtr + (size_t)i * 8 * K + k0),
                                             (lvoid*)&As[r * 128], 16, 0, 0);
            __builtin_amdgcn_global_load_lds((gvoid*)(bPtr + (size_t)i * 8 * K + k0),
                                             (lvoid*)&Bs[r * 128], 16, 0, 0);
        }
        __syncthreads();

        bf16x8 ah[4], al[4], bh[4], bl[4];
        #pragma unroll
        for (int m = 0; m < 4; ++m) {
            const int row = wr + m * 16 + lq;
            const int sw  = row & 7;
            ah[m] = *(const bf16x8*)&As[row * 128 + ((lk ^ sw) << 4)];
            al[m] = *(const bf16x8*)&As[row * 128 + (((4 + lk) ^ sw) << 4)];
        }
        #pragma unroll
        for (int n = 0; n < 4; ++n) {
            const int row = wc + n * 16 + lq;
            const int sw  = row & 7;
            bh[n] = *(const bf16x8*)&Bs[row * 128 + ((lk ^ sw) << 4)];
            bl[n] = *(const bf16x8*)&Bs[row * 128 + (((4 + lk) ^ sw) << 4)];
        }
        #pragma unroll
        for (int m = 0; m < 4; ++m)
            #pragma unroll
            for (int n = 0; n < 4; ++n) {
                acc[m][n] = __builtin_amdgcn_mfma_f32_16x16x32_bf16(ah[m], bh[n], acc[m][n], 0, 0, 0);
                acc[m][n] = __builtin_amdgcn_mfma_f32_16x16x32_bf16(ah[m], bl[n], acc[m][n], 0, 0, 0);
                acc[m][n] = __builtin_amdgcn_mfma_f32_16x16x32_bf16(al[m], bh[n], acc[m][n], 0, 0, 0);
            }
    }

    #pragma unroll
    for (int m = 0; m < 4; ++m)
        #pragma unroll
        for (int ri = 0; ri < 4; ++ri) {
            const int row = bm + wr + m * 16 + lk * 4 + ri;
            #pragma unroll
            for (int n = 0; n < 4; ++n) {
                const int col = bn + wc + n * 16 + lq;
                if (OUT_BF16)
                    ((unsigned short*)Cout)[(size_t)row * N + col] = f2bf(acc[m][n][ri]);
                else
                    ((float*)Cout)[(size_t)row * N + col] = acc[m][n][ri];
            }
        }
}

// ---------------------------------------------------------------------------
// bf16-MFMA flash attention. 8 waves, Q-tile 128 (16/wave), KV-tile 64,
// double-buffered K (global_load_lds) and V (reg-staged transpose).
// V-tile swizzle VSWZ spreads banks on BOTH the transpose-write (dh=4lq+j)
// and the PV read (dh=dt*16+lq) lane patterns.
// ---------------------------------------------------------------------------
__global__ __launch_bounds__(512)
void attn_mfma(const unsigned short* __restrict__ qkv,
               unsigned short* __restrict__ yhi, unsigned short* __restrict__ ylo) {
    const int bh  = blockIdx.y;
    const int b   = bh / NH;
    const int h   = bh % NH;
    const int qt  = blockIdx.x;           // Q-tile of 128 rows
    const int tid = threadIdx.x;
    const int w    = tid >> 6;            // 0..7
    const int lane = tid & 63;
    const int lq   = lane & 15;
    const int lk   = lane >> 4;

    __shared__ unsigned char Ks [2][64 * 128];  // bf16 [key][dh], swizzled, dbuf
    __shared__ unsigned char Vts[2][64 * 128];  // bf16 [dh][key], VSWZ, dbuf
    __shared__ unsigned char QPs[128 * 128];    // Q tile 128 rows; then P (8 x 2KB)

    // ---- stage Q (bf16 copy, swizzled): 1024 chunks of 16B, 512 thr x 2 ----
    #pragma unroll
    for (int it = 0; it < 2; ++it) {
        const int c   = tid + 512 * it;
        const int row = c >> 3, slot = c & 7;
        const bf16x8 v = *(const bf16x8*)&qkv[(size_t)(b * T + qt * 128 + row) * (3 * D) + h * DH + slot * 8];
        *(bf16x8*)&QPs[row * 128 + ((slot ^ (row & 7)) << 4)] = v;
    }

    // per-lane pre-swizzled source for K global_load_lds (1 instr/wave, 8 rows)
    const int srow   = lane >> 3;
    const int schunk = (lane & 7) ^ srow;
    const unsigned short* kBase = qkv + (size_t)(b * T + w * 8 + srow) * (3 * D) + D + h * DH + schunk * 8;
    // V staging: thread covers keys w*8+lk*2+{0,1}, dh lq*4..lq*4+3
    const unsigned short* vBase = qkv + (size_t)(b * T + w * 8 + lk * 2) * (3 * D) + 2 * D + h * DH + lq * 4;

    // ---- prologue: stage tile 0 into buffer 0 ----
    __builtin_amdgcn_global_load_lds((gvoid*)kBase, (lvoid*)&Ks[0][(w * 8) * 128], 16, 0, 0);
    u16x4 vr[2];
    #pragma unroll
    for (int i = 0; i < 2; ++i)
        vr[i] = *(const u16x4*)(vBase + (size_t)i * (3 * D));
    #pragma unroll
    for (int j = 0; j < 4; ++j) {
        const int dh = lq * 4 + j;
        const unsigned int pk = (unsigned int)vr[0][j] | ((unsigned int)vr[1][j] << 16);
        *(unsigned int*)&Vts[0][(dh * 128 + w * 16 + lk * 4) ^ VSWZ(dh)] = pk;
    }
    __syncthreads();

    // ---- Q fragments (wave w owns rows w*16..w*16+15) ----
    bf16x8 qf[2];
    #pragma unroll
    for (int ks = 0; ks < 2; ++ks) {
        const int row = w * 16 + lq;
        qf[ks] = *(const bf16x8*)&QPs[row * 128 + (((ks * 4 + lk) ^ (row & 7)) << 4)];
    }

    f32x4 o[4];
    #pragma unroll
    for (int dt = 0; dt < 4; ++dt) o[dt] = f32x4{0.f, 0.f, 0.f, 0.f};
    float m_r = -1e30f, l_r = 0.f;

    unsigned char* Pw = &QPs[w * 2048];

    for (int t = 0; t < T / 64; ++t) {
        const int c = t & 1;
        const bool more = (t + 1 < T / 64);
        // ---- issue next-tile staging early (hides under compute) ----
        if (more) {
            const int ktn = (t + 1) * 64;
            __builtin_amdgcn_global_load_lds((gvoid*)(kBase + (size_t)ktn * (3 * D)),
                                             (lvoid*)&Ks[c ^ 1][(w * 8) * 128], 16, 0, 0);
            #pragma unroll
            for (int i = 0; i < 2; ++i)
                vr[i] = *(const u16x4*)(vBase + (size_t)(ktn + i) * (3 * D));
        }

        // ---- S^T = K Q (swapped): lane owns 16 logits of query lq ----
        f32x4 s[4];
        #pragma unroll
        for (int ct = 0; ct < 4; ++ct) s[ct] = f32x4{0.f, 0.f, 0.f, 0.f};
        __builtin_amdgcn_s_setprio(1);
        #pragma unroll
        for (int ks = 0; ks < 2; ++ks) {
            #pragma unroll
            for (int ct = 0; ct < 4; ++ct) {
                const int key = ct * 16 + lq;
                const bf16x8 kf = *(const bf16x8*)&Ks[c][key * 128 + (((ks * 4 + lk) ^ (key & 7)) << 4)];
                s[ct] = __builtin_amdgcn_mfma_f32_16x16x32_bf16(kf, qf[ks], s[ct], 0, 0, 0);
            }
        }
        __builtin_amdgcn_s_setprio(0);

        // ---- online softmax (raw-logit domain) ----
        float v16 = s[0][0];
        #pragma unroll
        for (int ct = 0; ct < 4; ++ct)
            #pragma unroll
            for (int r = 0; r < 4; ++r) v16 = fmaxf(v16, s[ct][r]);
        v16 = fmaxf(v16, __shfl_xor(v16, 16));
        v16 = fmaxf(v16, __shfl_xor(v16, 32));
        if (__any(v16 > m_r)) {
            const float mnew = fmaxf(m_r, v16);
            const float corr = exp2_fast((m_r - mnew) * C_EXP);
            m_r = mnew;
            l_r *= corr;
            float corrO[4];
            #pragma unroll
            for (int r = 0; r < 4; ++r) corrO[r] = __shfl(corr, lk * 4 + r);
            #pragma unroll
            for (int dt = 0; dt < 4; ++dt)
                #pragma unroll
                for (int r = 0; r < 4; ++r) o[dt][r] *= corrO[r];
        }
        const float mC = m_r * C_EXP;
        float p[4][4];
        float tsum = 0.f;
        #pragma unroll
        for (int ct = 0; ct < 4; ++ct)
            #pragma unroll
            for (int r = 0; r < 4; ++r) {
                p[ct][r] = exp2_fast(__builtin_fmaf(s[ct][r], C_EXP, -mC));
                tsum += p[ct][r];
            }
        tsum += __shfl_xor(tsum, 16);
        tsum += __shfl_xor(tsum, 32);
        l_r += tsum;

        // ---- P pack (v_cvt_pk_bf16_f32) + 4x ds_write_b64 ----
        #pragma unroll
        for (int ct = 0; ct < 4; ++ct) {
            uint2 pk2;
            asm("v_cvt_pk_bf16_f32 %0, %1, %2" : "=v"(pk2.x) : "v"(p[ct][0]), "v"(p[ct][1]));
            asm("v_cvt_pk_bf16_f32 %0, %1, %2" : "=v"(pk2.y) : "v"(p[ct][2]), "v"(p[ct][3]));
            *(uint2*)&Pw[(lq * 128 + ct * 32 + lk * 8) ^ ((lq & 7) << 4)] = pk2;
        }
        asm volatile("s_waitcnt lgkmcnt(0)" ::: "memory");
        __builtin_amdgcn_sched_barrier(0);

        // ---- O += P V ----
        __builtin_amdgcn_s_setprio(1);
        #pragma unroll
        for (int ks = 0; ks < 2; ++ks) {
            const bf16x8 pf = *(const bf16x8*)&Pw[(lq * 128 + ks * 64 + lk * 16) ^ ((lq & 7) << 4)];
            #pragma unroll
            for (int dt = 0; dt < 4; ++dt) {
                const int dh = dt * 16 + lq;
                const bf16x8 vf = *(const bf16x8*)&Vts[c][(dh * 128 + ks * 64 + lk * 16) ^ VSWZ(dh)];
                o[dt] = __builtin_amdgcn_mfma_f32_16x16x32_bf16(pf, vf, o[dt], 0, 0, 0);
            }
        }
        __builtin_amdgcn_s_setprio(0);

        // ---- write next V tile into other buffer (vmcnt auto-waited) ----
        if (more) {
            #pragma unroll
            for (int j = 0; j < 4; ++j) {
                const int dh = lq * 4 + j;
                const unsigned int pk = (unsigned int)vr[0][j] | ((unsigned int)vr[1][j] << 16);
                *(unsigned int*)&Vts[c ^ 1][(dh * 128 + w * 16 + lk * 4) ^ VSWZ(dh)] = pk;
            }
        }
        __syncthreads();   // one barrier per tile
    }

    // ---- epilogue: O/l -> y hi/lo bf16 ----
    const float inv = 1.0f / l_r;
    float invO[4];
    #pragma unroll
    for (int r = 0; r < 4; ++r) invO[r] = __shfl(inv, lk * 4 + r);
    #pragma unroll
    for (int r = 0; r < 4; ++r) {
        const int row = qt * 128 + w * 16 + lk * 4 + r;
        const size_t base = (size_t)(b * T + row) * D + h * DH;
        #pragma unroll
        for (int dt = 0; dt < 4; ++dt) {
            const float val = o[dt][r] * invO[r];
            const unsigned short hv = f2bf(val);
            yhi[base + dt * 16 + lq] = hv;
            ylo[base + dt * 16 + lq] = f2bf(val - bf2f(hv));
        }
    }
}

// ---------------------------------------------------------------------------
extern "C" void kernel_launch(void* const* d_in, const int* in_sizes, int n_in,
                              void* d_out, int out_size, void* d_ws, size_t ws_size,
                              hipStream_t stream) {
    const float* x     = (const float*)d_in[0];
    const float* w_qkv = (const float*)d_in[1];
    const float* w_out = (const float*)d_in[2];

    unsigned short* Xhi = (unsigned short*)d_ws;              // M*D (reused as Yhi)
    unsigned short* Xlo = Xhi + (size_t)MROWS * D;            // M*D (reused as Ylo)
    unsigned short* Wqh = Xlo + (size_t)MROWS * D;            // 3D*D (N x K)
    unsigned short* Wql = Wqh + (size_t)3 * D * D;
    unsigned short* Woh = Wql + (size_t)3 * D * D;            // D*D
    unsigned short* Wol = Woh + (size_t)D * D;
    unsigned short* QKV = Wol + (size_t)D * D;                // M*3D bf16

    split_f32<<<2048, 256, 0, stream>>>(x, Xhi, Xlo, MROWS * D / 4);
    split_tr<<<dim3(3 * D / 32, D / 32), 256, 0, stream>>>(w_qkv, Wqh, Wql, D, 3 * D);
    split_tr<<<dim3(D / 32, D / 32), 256, 0, stream>>>(w_out, Woh, Wol, D, D);

    gemm_split<true><<<dim3(3 * D / 128, MROWS / 128), 256, 0, stream>>>(
        Xhi, Xlo, Wqh, Wql, QKV, MROWS, 3 * D, D);

    attn_mfma<<<dim3(T / 128, B * NH), 512, 0, stream>>>(QKV, Xhi, Xlo);

    gemm_split<false><<<dim3(D / 128, MROWS / 128), 256, 0, stream>>>(
        Xhi, Xlo, Woh, Wol, d_out, MROWS, D, D);
}

// Round 9
// 349.009 us; speedup vs baseline: 8.8785x; 1.0511x over previous
//
#include <hip/hip_runtime.h>

#define B  4
#define T  2048
#define D  1024
#define NH 16
#define DH 64
#define MROWS (B*T)   // 8192

typedef __attribute__((ext_vector_type(8))) short bf16x8;
typedef __attribute__((ext_vector_type(4))) float f32x4;
typedef __attribute__((ext_vector_type(4))) unsigned short u16x4;
typedef __attribute__((address_space(1))) const void gvoid;
typedef __attribute__((address_space(3))) void lvoid;

#define C_EXP 0.18033688011112042f   // 0.125 * log2(e)
// V-tile swizzle: must spread when dh = 4*lq+j (write) AND dh = dt*16+lq (read)
#define VSWZ(dh) (((((dh) ^ ((dh) >> 2)) & 7)) << 4)

__device__ inline unsigned short f2bf(float f) {
    union { float f; unsigned int u; } v; v.f = f;
    unsigned int r = v.u + 0x7fff + ((v.u >> 16) & 1);   // RNE
    return (unsigned short)(r >> 16);
}
__device__ inline float bf2f(unsigned short u) {
    union { unsigned int u; float f; } v; v.u = ((unsigned int)u) << 16;
    return v.f;
}
__device__ inline float exp2_fast(float x) {
    float r;
    asm("v_exp_f32 %0, %1" : "=v"(r) : "v"(x));   // D = 2^S0
    return r;
}

// ---------------------------------------------------------------------------
// Split fp32 array into bf16 hi + bf16 lo (lo = bf16(x - hi)).
// ---------------------------------------------------------------------------
__global__ __launch_bounds__(256)
void split_f32(const float* __restrict__ in, unsigned short* __restrict__ hi,
               unsigned short* __restrict__ lo, int n4) {
    for (int i = blockIdx.x * 256 + threadIdx.x; i < n4; i += gridDim.x * 256) {
        const float4 v = ((const float4*)in)[i];
        ushort4 h, l;
        h.x = f2bf(v.x); l.x = f2bf(v.x - bf2f(h.x));
        h.y = f2bf(v.y); l.y = f2bf(v.y - bf2f(h.y));
        h.z = f2bf(v.z); l.z = f2bf(v.z - bf2f(h.z));
        h.w = f2bf(v.w); l.w = f2bf(v.w - bf2f(h.w));
        ((ushort4*)hi)[i] = h;
        ((ushort4*)lo)[i] = l;
    }
}

// ---------------------------------------------------------------------------
// Transpose (K x N fp32) -> (N x K) bf16 hi/lo, 32x32 LDS tiles.
// ---------------------------------------------------------------------------
__global__ __launch_bounds__(256)
void split_tr(const float* __restrict__ Wm, unsigned short* __restrict__ hi,
              unsigned short* __restrict__ lo, int K, int N) {
    __shared__ float Tl[32][36];
    const int nt = blockIdx.x * 32, kt = blockIdx.y * 32;
    const int t = threadIdx.x;
    {
        const int r = t >> 3, c = (t & 7) * 4;
        const float4 v = *(const float4*)&Wm[(size_t)(kt + r) * N + nt + c];
        Tl[r][c] = v.x; Tl[r][c + 1] = v.y; Tl[r][c + 2] = v.z; Tl[r][c + 3] = v.w;
    }
    __syncthreads();
    {
        const int nl = t >> 3, k4 = (t & 7) * 4;
        const float v0 = Tl[k4 + 0][nl], v1 = Tl[k4 + 1][nl];
        const float v2 = Tl[k4 + 2][nl], v3 = Tl[k4 + 3][nl];
        ushort4 h, l;
        h.x = f2bf(v0); l.x = f2bf(v0 - bf2f(h.x));
        h.y = f2bf(v1); l.y = f2bf(v1 - bf2f(h.y));
        h.z = f2bf(v2); l.z = f2bf(v2 - bf2f(h.z));
        h.w = f2bf(v3); l.w = f2bf(v3 - bf2f(h.w));
        const size_t o = (size_t)(nt + nl) * K + kt + k4;
        *(ushort4*)&hi[o] = h;
        *(ushort4*)&lo[o] = l;
    }
}

// ---------------------------------------------------------------------------
// Split-bf16 MFMA GEMM, 2-phase double-buffered: C = A@B, 3 MFMA passes.
// A ~ Ahi+Alo (MxK), B^T ~ Bthi+Btlo (NxK). 128x128 tile, 4 waves, BK=32.
// Tile t+1 is staged via global_load_lds into buf[cur^1] BEFORE computing
// tile t from buf[cur]; one __syncthreads per K-step drains both.
// XCD-swizzled block mapping (nwg % 8 == 0 for both launches).
// ---------------------------------------------------------------------------
template<bool OUT_BF16>
__global__ __launch_bounds__(256)
void gemm_split(const unsigned short* __restrict__ Ahi, const unsigned short* __restrict__ Alo,
                const unsigned short* __restrict__ Bthi, const unsigned short* __restrict__ Btlo,
                void* __restrict__ Cout, int M, int N, int K) {
    __shared__ unsigned char As[2][128 * 128];
    __shared__ unsigned char Bs[2][128 * 128];
    const int tid  = threadIdx.x;
    const int w    = tid >> 6;
    const int lane = tid & 63;
    const int lq   = lane & 15;
    const int lk   = lane >> 4;

    // XCD-aware swizzle (T1): contiguous tile chunks per XCD.
    const int gx  = gridDim.x;
    const int nwg = gx * gridDim.y;
    int lin = blockIdx.y * gx + blockIdx.x;
    lin = (lin & 7) * (nwg >> 3) + (lin >> 3);
    const int bm = (lin / gx) * 128;
    const int bn = (lin % gx) * 128;

    // pre-swizzled staging source pattern: lane l -> LDS (row=l>>3, slot=l&7);
    // content must be chunk (slot ^ row) of that row (rows 8-aligned).
    const int srow   = lane >> 3;
    const int sidx   = (lane & 7) ^ srow;   // 0..7: 0-3 = hi chunks, 4-7 = lo
    const int shalf  = sidx >> 2;
    const int schunk = sidx & 3;
    const unsigned short* aPtr = (shalf ? Alo : Ahi) + (size_t)(bm + w * 32 + srow) * K + schunk * 8;
    const unsigned short* bPtr = (shalf ? Btlo : Bthi) + (size_t)(bn + w * 32 + srow) * K + schunk * 8;

    f32x4 acc[4][4];
    #pragma unroll
    for (int m = 0; m < 4; ++m)
        #pragma unroll
        for (int n = 0; n < 4; ++n) acc[m][n] = f32x4{0.f, 0.f, 0.f, 0.f};

    const int wr = (w >> 1) * 64, wc = (w & 1) * 64;

    // ---- prologue: stage k0=0 into buffer 0 ----
    #pragma unroll
    for (int i = 0; i < 4; ++i) {
        const int r = w * 32 + i * 8;
        __builtin_amdgcn_global_load_lds((gvoid*)(aPtr + (size_t)i * 8 * K),
                                         (lvoid*)&As[0][r * 128], 16, 0, 0);
        __builtin_amdgcn_global_load_lds((gvoid*)(bPtr + (size_t)i * 8 * K),
                                         (lvoid*)&Bs[0][r * 128], 16, 0, 0);
    }
    __syncthreads();

    int cur = 0;
    for (int k0 = 0; k0 < K; k0 += 32) {
        // ---- issue next-tile staging early (latency hides under compute) ----
        if (k0 + 32 < K) {
            #pragma unroll
            for (int i = 0; i < 4; ++i) {
                const int r = w * 32 + i * 8;
                __builtin_amdgcn_global_load_lds((gvoid*)(aPtr + (size_t)i * 8 * K + k0 + 32),
                                                 (lvoid*)&As[cur ^ 1][r * 128], 16, 0, 0);
                __builtin_amdgcn_global_load_lds((gvoid*)(bPtr + (size_t)i * 8 * K + k0 + 32),
                                                 (lvoid*)&Bs[cur ^ 1][r * 128], 16, 0, 0);
            }
        }

        const unsigned char* Ac = As[cur];
        const unsigned char* Bc = Bs[cur];
        bf16x8 ah[4], al[4], bh[4], bl[4];
        #pragma unroll
        for (int m = 0; m < 4; ++m) {
            const int row = wr + m * 16 + lq;
            const int sw  = row & 7;
            ah[m] = *(const bf16x8*)&Ac[row * 128 + ((lk ^ sw) << 4)];
            al[m] = *(const bf16x8*)&Ac[row * 128 + (((4 + lk) ^ sw) << 4)];
        }
        #pragma unroll
        for (int n = 0; n < 4; ++n) {
            const int row = wc + n * 16 + lq;
            const int sw  = row & 7;
            bh[n] = *(const bf16x8*)&Bc[row * 128 + ((lk ^ sw) << 4)];
            bl[n] = *(const bf16x8*)&Bc[row * 128 + (((4 + lk) ^ sw) << 4)];
        }
        __builtin_amdgcn_s_setprio(1);
        #pragma unroll
        for (int m = 0; m < 4; ++m)
            #pragma unroll
            for (int n = 0; n < 4; ++n) {
                acc[m][n] = __builtin_amdgcn_mfma_f32_16x16x32_bf16(ah[m], bh[n], acc[m][n], 0, 0, 0);
                acc[m][n] = __builtin_amdgcn_mfma_f32_16x16x32_bf16(ah[m], bl[n], acc[m][n], 0, 0, 0);
                acc[m][n] = __builtin_amdgcn_mfma_f32_16x16x32_bf16(al[m], bh[n], acc[m][n], 0, 0, 0);
            }
        __builtin_amdgcn_s_setprio(0);
        __syncthreads();   // drains next-tile loads + protects buf reuse
        cur ^= 1;
    }

    #pragma unroll
    for (int m = 0; m < 4; ++m)
        #pragma unroll
        for (int ri = 0; ri < 4; ++ri) {
            const int row = bm + wr + m * 16 + lk * 4 + ri;
            #pragma unroll
            for (int n = 0; n < 4; ++n) {
                const int col = bn + wc + n * 16 + lq;
                if (OUT_BF16)
                    ((unsigned short*)Cout)[(size_t)row * N + col] = f2bf(acc[m][n][ri]);
                else
                    ((float*)Cout)[(size_t)row * N + col] = acc[m][n][ri];
            }
        }
}

// ---------------------------------------------------------------------------
// bf16-MFMA flash attention (unchanged from round 8). 8 waves, Q-tile 128,
// KV-tile 64, double-buffered K (global_load_lds) and V (reg-staged).
// ---------------------------------------------------------------------------
__global__ __launch_bounds__(512)
void attn_mfma(const unsigned short* __restrict__ qkv,
               unsigned short* __restrict__ yhi, unsigned short* __restrict__ ylo) {
    const int bh  = blockIdx.y;
    const int b   = bh / NH;
    const int h   = bh % NH;
    const int qt  = blockIdx.x;           // Q-tile of 128 rows
    const int tid = threadIdx.x;
    const int w    = tid >> 6;            // 0..7
    const int lane = tid & 63;
    const int lq   = lane & 15;
    const int lk   = lane >> 4;

    __shared__ unsigned char Ks [2][64 * 128];  // bf16 [key][dh], swizzled, dbuf
    __shared__ unsigned char Vts[2][64 * 128];  // bf16 [dh][key], VSWZ, dbuf
    __shared__ unsigned char QPs[128 * 128];    // Q tile 128 rows; then P (8 x 2KB)

    // ---- stage Q (bf16 copy, swizzled): 1024 chunks of 16B, 512 thr x 2 ----
    #pragma unroll
    for (int it = 0; it < 2; ++it) {
        const int c   = tid + 512 * it;
        const int row = c >> 3, slot = c & 7;
        const bf16x8 v = *(const bf16x8*)&qkv[(size_t)(b * T + qt * 128 + row) * (3 * D) + h * DH + slot * 8];
        *(bf16x8*)&QPs[row * 128 + ((slot ^ (row & 7)) << 4)] = v;
    }

    // per-lane pre-swizzled source for K global_load_lds (1 instr/wave, 8 rows)
    const int srow   = lane >> 3;
    const int schunk = (lane & 7) ^ srow;
    const unsigned short* kBase = qkv + (size_t)(b * T + w * 8 + srow) * (3 * D) + D + h * DH + schunk * 8;
    // V staging: thread covers keys w*8+lk*2+{0,1}, dh lq*4..lq*4+3
    const unsigned short* vBase = qkv + (size_t)(b * T + w * 8 + lk * 2) * (3 * D) + 2 * D + h * DH + lq * 4;

    // ---- prologue: stage tile 0 into buffer 0 ----
    __builtin_amdgcn_global_load_lds((gvoid*)kBase, (lvoid*)&Ks[0][(w * 8) * 128], 16, 0, 0);
    u16x4 vr[2];
    #pragma unroll
    for (int i = 0; i < 2; ++i)
        vr[i] = *(const u16x4*)(vBase + (size_t)i * (3 * D));
    #pragma unroll
    for (int j = 0; j < 4; ++j) {
        const int dh = lq * 4 + j;
        const unsigned int pk = (unsigned int)vr[0][j] | ((unsigned int)vr[1][j] << 16);
        *(unsigned int*)&Vts[0][(dh * 128 + w * 16 + lk * 4) ^ VSWZ(dh)] = pk;
    }
    __syncthreads();

    // ---- Q fragments (wave w owns rows w*16..w*16+15) ----
    bf16x8 qf[2];
    #pragma unroll
    for (int ks = 0; ks < 2; ++ks) {
        const int row = w * 16 + lq;
        qf[ks] = *(const bf16x8*)&QPs[row * 128 + (((ks * 4 + lk) ^ (row & 7)) << 4)];
    }

    f32x4 o[4];
    #pragma unroll
    for (int dt = 0; dt < 4; ++dt) o[dt] = f32x4{0.f, 0.f, 0.f, 0.f};
    float m_r = -1e30f, l_r = 0.f;

    unsigned char* Pw = &QPs[w * 2048];

    for (int t = 0; t < T / 64; ++t) {
        const int c = t & 1;
        const bool more = (t + 1 < T / 64);
        // ---- issue next-tile staging early (hides under compute) ----
        if (more) {
            const int ktn = (t + 1) * 64;
            __builtin_amdgcn_global_load_lds((gvoid*)(kBase + (size_t)ktn * (3 * D)),
                                             (lvoid*)&Ks[c ^ 1][(w * 8) * 128], 16, 0, 0);
            #pragma unroll
            for (int i = 0; i < 2; ++i)
                vr[i] = *(const u16x4*)(vBase + (size_t)(ktn + i) * (3 * D));
        }

        // ---- S^T = K Q (swapped): lane owns 16 logits of query lq ----
        f32x4 s[4];
        #pragma unroll
        for (int ct = 0; ct < 4; ++ct) s[ct] = f32x4{0.f, 0.f, 0.f, 0.f};
        __builtin_amdgcn_s_setprio(1);
        #pragma unroll
        for (int ks = 0; ks < 2; ++ks) {
            #pragma unroll
            for (int ct = 0; ct < 4; ++ct) {
                const int key = ct * 16 + lq;
                const bf16x8 kf = *(const bf16x8*)&Ks[c][key * 128 + (((ks * 4 + lk) ^ (key & 7)) << 4)];
                s[ct] = __builtin_amdgcn_mfma_f32_16x16x32_bf16(kf, qf[ks], s[ct], 0, 0, 0);
            }
        }
        __builtin_amdgcn_s_setprio(0);

        // ---- online softmax (raw-logit domain) ----
        float v16 = s[0][0];
        #pragma unroll
        for (int ct = 0; ct < 4; ++ct)
            #pragma unroll
            for (int r = 0; r < 4; ++r) v16 = fmaxf(v16, s[ct][r]);
        v16 = fmaxf(v16, __shfl_xor(v16, 16));
        v16 = fmaxf(v16, __shfl_xor(v16, 32));
        if (__any(v16 > m_r)) {
            const float mnew = fmaxf(m_r, v16);
            const float corr = exp2_fast((m_r - mnew) * C_EXP);
            m_r = mnew;
            l_r *= corr;
            float corrO[4];
            #pragma unroll
            for (int r = 0; r < 4; ++r) corrO[r] = __shfl(corr, lk * 4 + r);
            #pragma unroll
            for (int dt = 0; dt < 4; ++dt)
                #pragma unroll
                for (int r = 0; r < 4; ++r) o[dt][r] *= corrO[r];
        }
        const float mC = m_r * C_EXP;
        float p[4][4];
        float tsum = 0.f;
        #pragma unroll
        for (int ct = 0; ct < 4; ++ct)
            #pragma unroll
            for (int r = 0; r < 4; ++r) {
                p[ct][r] = exp2_fast(__builtin_fmaf(s[ct][r], C_EXP, -mC));
                tsum += p[ct][r];
            }
        tsum += __shfl_xor(tsum, 16);
        tsum += __shfl_xor(tsum, 32);
        l_r += tsum;

        // ---- P pack (v_cvt_pk_bf16_f32) + 4x ds_write_b64 ----
        #pragma unroll
        for (int ct = 0; ct < 4; ++ct) {
            uint2 pk2;
            asm("v_cvt_pk_bf16_f32 %0, %1, %2" : "=v"(pk2.x) : "v"(p[ct][0]), "v"(p[ct][1]));
            asm("v_cvt_pk_bf16_f32 %0, %1, %2" : "=v"(pk2.y) : "v"(p[ct][2]), "v"(p[ct][3]));
            *(uint2*)&Pw[(lq * 128 + ct * 32 + lk * 8) ^ ((lq & 7) << 4)] = pk2;
        }
        asm volatile("s_waitcnt lgkmcnt(0)" ::: "memory");
        __builtin_amdgcn_sched_barrier(0);

        // ---- O += P V ----
        __builtin_amdgcn_s_setprio(1);
        #pragma unroll
        for (int ks = 0; ks < 2; ++ks) {
            const bf16x8 pf = *(const bf16x8*)&Pw[(lq * 128 + ks * 64 + lk * 16) ^ ((lq & 7) << 4)];
            #pragma unroll
            for (int dt = 0; dt < 4; ++dt) {
                const int dh = dt * 16 + lq;
                const bf16x8 vf = *(const bf16x8*)&Vts[c][(dh * 128 + ks * 64 + lk * 16) ^ VSWZ(dh)];
                o[dt] = __builtin_amdgcn_mfma_f32_16x16x32_bf16(pf, vf, o[dt], 0, 0, 0);
            }
        }
        __builtin_amdgcn_s_setprio(0);

        // ---- write next V tile into other buffer (vmcnt auto-waited) ----
        if (more) {
            #pragma unroll
            for (int j = 0; j < 4; ++j) {
                const int dh = lq * 4 + j;
                const unsigned int pk = (unsigned int)vr[0][j] | ((unsigned int)vr[1][j] << 16);
                *(unsigned int*)&Vts[c ^ 1][(dh * 128 + w * 16 + lk * 4) ^ VSWZ(dh)] = pk;
            }
        }
        __syncthreads();   // one barrier per tile
    }

    // ---- epilogue: O/l -> y hi/lo bf16 ----
    const float inv = 1.0f / l_r;
    float invO[4];
    #pragma unroll
    for (int r = 0; r < 4; ++r) invO[r] = __shfl(inv, lk * 4 + r);
    #pragma unroll
    for (int r = 0; r < 4; ++r) {
        const int row = qt * 128 + w * 16 + lk * 4 + r;
        const size_t base = (size_t)(b * T + row) * D + h * DH;
        #pragma unroll
        for (int dt = 0; dt < 4; ++dt) {
            const float val = o[dt][r] * invO[r];
            const unsigned short hv = f2bf(val);
            yhi[base + dt * 16 + lq] = hv;
            ylo[base + dt * 16 + lq] = f2bf(val - bf2f(hv));
        }
    }
}

// ---------------------------------------------------------------------------
extern "C" void kernel_launch(void* const* d_in, const int* in_sizes, int n_in,
                              void* d_out, int out_size, void* d_ws, size_t ws_size,
                              hipStream_t stream) {
    const float* x     = (const float*)d_in[0];
    const float* w_qkv = (const float*)d_in[1];
    const float* w_out = (const float*)d_in[2];

    unsigned short* Xhi = (unsigned short*)d_ws;              // M*D (reused as Yhi)
    unsigned short* Xlo = Xhi + (size_t)MROWS * D;            // M*D (reused as Ylo)
    unsigned short* Wqh = Xlo + (size_t)MROWS * D;            // 3D*D (N x K)
    unsigned short* Wql = Wqh + (size_t)3 * D * D;
    unsigned short* Woh = Wql + (size_t)3 * D * D;            // D*D
    unsigned short* Wol = Woh + (size_t)D * D;
    unsigned short* QKV = Wol + (size_t)D * D;                // M*3D bf16

    split_f32<<<2048, 256, 0, stream>>>(x, Xhi, Xlo, MROWS * D / 4);
    split_tr<<<dim3(3 * D / 32, D / 32), 256, 0, stream>>>(w_qkv, Wqh, Wql, D, 3 * D);
    split_tr<<<dim3(D / 32, D / 32), 256, 0, stream>>>(w_out, Woh, Wol, D, D);

    gemm_split<true><<<dim3(3 * D / 128, MROWS / 128), 256, 0, stream>>>(
        Xhi, Xlo, Wqh, Wql, QKV, MROWS, 3 * D, D);

    attn_mfma<<<dim3(T / 128, B * NH), 512, 0, stream>>>(QKV, Xhi, Xlo);

    gemm_split<false><<<dim3(D / 128, MROWS / 128), 256, 0, stream>>>(
        Xhi, Xlo, Woh, Wol, d_out, MROWS, D, D);
}

// Round 11
// 345.304 us; speedup vs baseline: 8.9738x; 1.0107x over previous
//
#include <hip/hip_runtime.h>

#define B  4
#define T  2048
#define D  1024
#define NH 16
#define DH 64
#define MROWS (B*T)   // 8192

typedef __attribute__((ext_vector_type(8))) short bf16x8;
typedef __attribute__((ext_vector_type(4))) float f32x4;
typedef __attribute__((ext_vector_type(4))) unsigned short u16x4;
typedef __attribute__((address_space(1))) const void gvoid;
typedef __attribute__((address_space(3))) void lvoid;

#define C_EXP 0.18033688011112042f   // 0.125 * log2(e)
// V-tile swizzle: must spread when dh = 4*lq+j (write) AND dh = dt*16+lq (read)
#define VSWZ(dh) (((((dh) ^ ((dh) >> 2)) & 7)) << 4)

__device__ inline unsigned short f2bf(float f) {
    union { float f; unsigned int u; } v; v.f = f;
    unsigned int r = v.u + 0x7fff + ((v.u >> 16) & 1);   // RNE
    return (unsigned short)(r >> 16);
}
__device__ inline float bf2f(unsigned short u) {
    union { unsigned int u; float f; } v; v.u = ((unsigned int)u) << 16;
    return v.f;
}
__device__ inline float exp2_fast(float x) {
    float r;
    asm("v_exp_f32 %0, %1" : "=v"(r) : "v"(x));   // D = 2^S0
    return r;
}

// ---------------------------------------------------------------------------
// Split fp32 array into bf16 hi + bf16 lo (lo = bf16(x - hi)).
// ---------------------------------------------------------------------------
__global__ __launch_bounds__(256)
void split_f32(const float* __restrict__ in, unsigned short* __restrict__ hi,
               unsigned short* __restrict__ lo, int n4) {
    for (int i = blockIdx.x * 256 + threadIdx.x; i < n4; i += gridDim.x * 256) {
        const float4 v = ((const float4*)in)[i];
        ushort4 h, l;
        h.x = f2bf(v.x); l.x = f2bf(v.x - bf2f(h.x));
        h.y = f2bf(v.y); l.y = f2bf(v.y - bf2f(h.y));
        h.z = f2bf(v.z); l.z = f2bf(v.z - bf2f(h.z));
        h.w = f2bf(v.w); l.w = f2bf(v.w - bf2f(h.w));
        ((ushort4*)hi)[i] = h;
        ((ushort4*)lo)[i] = l;
    }
}

// ---------------------------------------------------------------------------
// Transpose (K x N fp32) -> (N x K) bf16 hi/lo, 32x32 LDS tiles.
// ---------------------------------------------------------------------------
__global__ __launch_bounds__(256)
void split_tr(const float* __restrict__ Wm, unsigned short* __restrict__ hi,
              unsigned short* __restrict__ lo, int K, int N) {
    __shared__ float Tl[32][36];
    const int nt = blockIdx.x * 32, kt = blockIdx.y * 32;
    const int t = threadIdx.x;
    {
        const int r = t >> 3, c = (t & 7) * 4;
        const float4 v = *(const float4*)&Wm[(size_t)(kt + r) * N + nt + c];
        Tl[r][c] = v.x; Tl[r][c + 1] = v.y; Tl[r][c + 2] = v.z; Tl[r][c + 3] = v.w;
    }
    __syncthreads();
    {
        const int nl = t >> 3, k4 = (t & 7) * 4;
        const float v0 = Tl[k4 + 0][nl], v1 = Tl[k4 + 1][nl];
        const float v2 = Tl[k4 + 2][nl], v3 = Tl[k4 + 3][nl];
        ushort4 h, l;
        h.x = f2bf(v0); l.x = f2bf(v0 - bf2f(h.x));
        h.y = f2bf(v1); l.y = f2bf(v1 - bf2f(h.y));
        h.z = f2bf(v2); l.z = f2bf(v2 - bf2f(h.z));
        h.w = f2bf(v3); l.w = f2bf(v3 - bf2f(h.w));
        const size_t o = (size_t)(nt + nl) * K + kt + k4;
        *(ushort4*)&hi[o] = h;
        *(ushort4*)&lo[o] = l;
    }
}

// ---------------------------------------------------------------------------
// Split-bf16 MFMA GEMM, 4-phase counted-wait schedule (T3+T4 port).
// C = A@B, 3 MFMA passes (hi*hi + hi*lo + lo*hi). A ~ Ahi+Alo (MxK),
// B^T ~ Bthi+Btlo (NxK). BM=256, BN=128, BK=32, 8 waves, per-wave 64x64.
// Per K-tile: 4 phases, each {ds_read subtile | stage next tile (ph 0-1) ->
// raw s_barrier -> lgkmcnt(0) -> 12 MFMA -> s_barrier}; vmcnt(0) only at
// the K-tile boundary so staging loads stay in flight across barriers.
// ---------------------------------------------------------------------------
template<bool OUT_BF16>
__global__ __launch_bounds__(512, 2)
void gemm_split(const unsigned short* __restrict__ Ahi, const unsigned short* __restrict__ Alo,
                const unsigned short* __restrict__ Bthi, const unsigned short* __restrict__ Btlo,
                void* __restrict__ Cout, int M, int N, int K) {
    __shared__ unsigned char As[2][256 * 128];   // 256 rows x (hi 64B | lo 64B)
    __shared__ unsigned char Bs[2][128 * 128];   // 128 rows x (hi 64B | lo 64B)
    const int tid  = threadIdx.x;
    const int w    = tid >> 6;        // 0..7
    const int lane = tid & 63;
    const int lq   = lane & 15;
    const int lk   = lane >> 4;
    const int wm   = w >> 1;          // 0..3 -> 64-row band
    const int wn   = w & 1;           // 0..1 -> 64-col band

    // XCD-aware bijective swizzle (nwg % 8 == 0 for both launches).
    const int gx  = gridDim.x;
    const int nwg = gx * gridDim.y;
    int lin = blockIdx.y * gx + blockIdx.x;
    lin = (lin & 7) * (nwg >> 3) + (lin >> 3);
    const int bm = (lin / gx) * 256;
    const int bn = (lin % gx) * 128;

    // pre-swizzled staging source pattern: lane l -> LDS (row=l>>3, slot=l&7);
    // content must be chunk (slot ^ row) of that row (rows 8-aligned).
    const int srow   = lane >> 3;
    const int sidx   = (lane & 7) ^ srow;   // 0..7: 0-3 = hi chunks, 4-7 = lo
    const int shalf  = sidx >> 2;
    const int schunk = sidx & 3;
    const unsigned short* aPtr = (shalf ? Alo : Ahi) + (size_t)(bm + w * 32 + srow) * K + schunk * 8;
    const unsigned short* bPtr = (shalf ? Btlo : Bthi) + (size_t)(bn + w * 16 + srow) * K + schunk * 8;

    f32x4 acc[4][4];
    #pragma unroll
    for (int m = 0; m < 4; ++m)
        #pragma unroll
        for (int n = 0; n < 4; ++n) acc[m][n] = f32x4{0.f, 0.f, 0.f, 0.f};

    // ---- prologue: stage K-tile 0 into buffer 0 (A: 4 instr, B: 2 instr) ----
    #pragma unroll
    for (int i = 0; i < 4; ++i)
        __builtin_amdgcn_global_load_lds((gvoid*)(aPtr + (size_t)i * 8 * K),
                                         (lvoid*)&As[0][(w * 32 + i * 8) * 128], 16, 0, 0);
    #pragma unroll
    for (int i = 0; i < 2; ++i)
        __builtin_amdgcn_global_load_lds((gvoid*)(bPtr + (size_t)i * 8 * K),
                                         (lvoid*)&Bs[0][(w * 16 + i * 8) * 128], 16, 0, 0);
    __syncthreads();   // full drain once at prologue

    int cur = 0;
    const int NKT = K / 32;
    for (int kt = 0; kt < NKT; ++kt) {
        const bool more = (kt + 1 < NKT);
        const int k0n = (kt + 1) * 32;
        bf16x8 bh[4], bl[4];
        #pragma unroll
        for (int p = 0; p < 4; ++p) {
            // ---- ds-reads for this phase (from buf cur) ----
            bf16x8 ah, al;
            {
                const int row = wm * 64 + p * 16 + lq;
                const int sw  = row & 7;
                ah = *(const bf16x8*)&As[cur][row * 128 + ((lk ^ sw) << 4)];
                al = *(const bf16x8*)&As[cur][row * 128 + (((4 + lk) ^ sw) << 4)];
            }
            if (p == 0) {
                #pragma unroll
                for (int n = 0; n < 4; ++n) {
                    const int row = wn * 64 + n * 16 + lq;
                    const int sw  = row & 7;
                    bh[n] = *(const bf16x8*)&Bs[cur][row * 128 + ((lk ^ sw) << 4)];
                    bl[n] = *(const bf16x8*)&Bs[cur][row * 128 + (((4 + lk) ^ sw) << 4)];
                }
            }
            // ---- stage next K-tile into buf cur^1 (front-loaded, ph 0-1) ----
            if (more && p < 2) {
                const int i0 = p * 2;
                #pragma unroll
                for (int i = 0; i < 2; ++i)
                    __builtin_amdgcn_global_load_lds(
                        (gvoid*)(aPtr + (size_t)(i0 + i) * 8 * K + k0n),
                        (lvoid*)&As[cur ^ 1][(w * 32 + (i0 + i) * 8) * 128], 16, 0, 0);
                __builtin_amdgcn_global_load_lds(
                    (gvoid*)(bPtr + (size_t)p * 8 * K + k0n),
                    (lvoid*)&Bs[cur ^ 1][(w * 16 + p * 8) * 128], 16, 0, 0);
            }
            __builtin_amdgcn_s_barrier();
            asm volatile("s_waitcnt lgkmcnt(0)" ::: "memory");
            __builtin_amdgcn_sched_barrier(0);
            __builtin_amdgcn_s_setprio(1);
            #pragma unroll
            for (int n = 0; n < 4; ++n) {
                acc[p][n] = __builtin_amdgcn_mfma_f32_16x16x32_bf16(ah, bh[n], acc[p][n], 0, 0, 0);
                acc[p][n] = __builtin_amdgcn_mfma_f32_16x16x32_bf16(ah, bl[n], acc[p][n], 0, 0, 0);
                acc[p][n] = __builtin_amdgcn_mfma_f32_16x16x32_bf16(al, bh[n], acc[p][n], 0, 0, 0);
            }
            __builtin_amdgcn_s_setprio(0);
            if (p == 3)   // boundary: staged loads must be visible past this bar
                asm volatile("s_waitcnt vmcnt(0)" ::: "memory");
            __builtin_amdgcn_s_barrier();
        }
        cur ^= 1;
    }

    #pragma unroll
    for (int m = 0; m < 4; ++m)
        #pragma unroll
        for (int ri = 0; ri < 4; ++ri) {
            const int row = bm + wm * 64 + m * 16 + lk * 4 + ri;
            #pragma unroll
            for (int n = 0; n < 4; ++n) {
                const int col = bn + wn * 64 + n * 16 + lq;
                if (OUT_BF16)
                    ((unsigned short*)Cout)[(size_t)row * N + col] = f2bf(acc[m][n][ri]);
                else
                    ((float*)Cout)[(size_t)row * N + col] = acc[m][n][ri];
            }
        }
}

// ---------------------------------------------------------------------------
// bf16-MFMA flash attention (unchanged from round 8). 8 waves, Q-tile 128,
// KV-tile 64, double-buffered K (global_load_lds) and V (reg-staged).
// ---------------------------------------------------------------------------
__global__ __launch_bounds__(512)
void attn_mfma(const unsigned short* __restrict__ qkv,
               unsigned short* __restrict__ yhi, unsigned short* __restrict__ ylo) {
    const int bh  = blockIdx.y;
    const int b   = bh / NH;
    const int h   = bh % NH;
    const int qt  = blockIdx.x;           // Q-tile of 128 rows
    const int tid = threadIdx.x;
    const int w    = tid >> 6;            // 0..7
    const int lane = tid & 63;
    const int lq   = lane & 15;
    const int lk   = lane >> 4;

    __shared__ unsigned char Ks [2][64 * 128];  // bf16 [key][dh], swizzled, dbuf
    __shared__ unsigned char Vts[2][64 * 128];  // bf16 [dh][key], VSWZ, dbuf
    __shared__ unsigned char QPs[128 * 128];    // Q tile 128 rows; then P (8 x 2KB)

    // ---- stage Q (bf16 copy, swizzled): 1024 chunks of 16B, 512 thr x 2 ----
    #pragma unroll
    for (int it = 0; it < 2; ++it) {
        const int c   = tid + 512 * it;
        const int row = c >> 3, slot = c & 7;
        const bf16x8 v = *(const bf16x8*)&qkv[(size_t)(b * T + qt * 128 + row) * (3 * D) + h * DH + slot * 8];
        *(bf16x8*)&QPs[row * 128 + ((slot ^ (row & 7)) << 4)] = v;
    }

    // per-lane pre-swizzled source for K global_load_lds (1 instr/wave, 8 rows)
    const int srow   = lane >> 3;
    const int schunk = (lane & 7) ^ srow;
    const unsigned short* kBase = qkv + (size_t)(b * T + w * 8 + srow) * (3 * D) + D + h * DH + schunk * 8;
    // V staging: thread covers keys w*8+lk*2+{0,1}, dh lq*4..lq*4+3
    const unsigned short* vBase = qkv + (size_t)(b * T + w * 8 + lk * 2) * (3 * D) + 2 * D + h * DH + lq * 4;

    // ---- prologue: stage tile 0 into buffer 0 ----
    __builtin_amdgcn_global_load_lds((gvoid*)kBase, (lvoid*)&Ks[0][(w * 8) * 128], 16, 0, 0);
    u16x4 vr[2];
    #pragma unroll
    for (int i = 0; i < 2; ++i)
        vr[i] = *(const u16x4*)(vBase + (size_t)i * (3 * D));
    #pragma unroll
    for (int j = 0; j < 4; ++j) {
        const int dh = lq * 4 + j;
        const unsigned int pk = (unsigned int)vr[0][j] | ((unsigned int)vr[1][j] << 16);
        *(unsigned int*)&Vts[0][(dh * 128 + w * 16 + lk * 4) ^ VSWZ(dh)] = pk;
    }
    __syncthreads();

    // ---- Q fragments (wave w owns rows w*16..w*16+15) ----
    bf16x8 qf[2];
    #pragma unroll
    for (int ks = 0; ks < 2; ++ks) {
        const int row = w * 16 + lq;
        qf[ks] = *(const bf16x8*)&QPs[row * 128 + (((ks * 4 + lk) ^ (row & 7)) << 4)];
    }

    f32x4 o[4];
    #pragma unroll
    for (int dt = 0; dt < 4; ++dt) o[dt] = f32x4{0.f, 0.f, 0.f, 0.f};
    float m_r = -1e30f, l_r = 0.f;

    unsigned char* Pw = &QPs[w * 2048];

    for (int t = 0; t < T / 64; ++t) {
        const int c = t & 1;
        const bool more = (t + 1 < T / 64);
        // ---- issue next-tile staging early (hides under compute) ----
        if (more) {
            const int ktn = (t + 1) * 64;
            __builtin_amdgcn_global_load_lds((gvoid*)(kBase + (size_t)ktn * (3 * D)),
                                             (lvoid*)&Ks[c ^ 1][(w * 8) * 128], 16, 0, 0);
            #pragma unroll
            for (int i = 0; i < 2; ++i)
                vr[i] = *(const u16x4*)(vBase + (size_t)(ktn + i) * (3 * D));
        }

        // ---- S^T = K Q (swapped): lane owns 16 logits of query lq ----
        f32x4 s[4];
        #pragma unroll
        for (int ct = 0; ct < 4; ++ct) s[ct] = f32x4{0.f, 0.f, 0.f, 0.f};
        __builtin_amdgcn_s_setprio(1);
        #pragma unroll
        for (int ks = 0; ks < 2; ++ks) {
            #pragma unroll
            for (int ct = 0; ct < 4; ++ct) {
                const int key = ct * 16 + lq;
                const bf16x8 kf = *(const bf16x8*)&Ks[c][key * 128 + (((ks * 4 + lk) ^ (key & 7)) << 4)];
                s[ct] = __builtin_amdgcn_mfma_f32_16x16x32_bf16(kf, qf[ks], s[ct], 0, 0, 0);
            }
        }
        __builtin_amdgcn_s_setprio(0);

        // ---- online softmax (raw-logit domain) ----
        float v16 = s[0][0];
        #pragma unroll
        for (int ct = 0; ct < 4; ++ct)
            #pragma unroll
            for (int r = 0; r < 4; ++r) v16 = fmaxf(v16, s[ct][r]);
        v16 = fmaxf(v16, __shfl_xor(v16, 16));
        v16 = fmaxf(v16, __shfl_xor(v16, 32));
        if (__any(v16 > m_r)) {
            const float mnew = fmaxf(m_r, v16);
            const float corr = exp2_fast((m_r - mnew) * C_EXP);
            m_r = mnew;
            l_r *= corr;
            float corrO[4];
            #pragma unroll
            for (int r = 0; r < 4; ++r) corrO[r] = __shfl(corr, lk * 4 + r);
            #pragma unroll
            for (int dt = 0; dt < 4; ++dt)
                #pragma unroll
                for (int r = 0; r < 4; ++r) o[dt][r] *= corrO[r];
        }
        const float mC = m_r * C_EXP;
        float p[4][4];
        float tsum = 0.f;
        #pragma unroll
        for (int ct = 0; ct < 4; ++ct)
            #pragma unroll
            for (int r = 0; r < 4; ++r) {
                p[ct][r] = exp2_fast(__builtin_fmaf(s[ct][r], C_EXP, -mC));
                tsum += p[ct][r];
            }
        tsum += __shfl_xor(tsum, 16);
        tsum += __shfl_xor(tsum, 32);
        l_r += tsum;

        // ---- P pack (v_cvt_pk_bf16_f32) + 4x ds_write_b64 ----
        #pragma unroll
        for (int ct = 0; ct < 4; ++ct) {
            uint2 pk2;
            asm("v_cvt_pk_bf16_f32 %0, %1, %2" : "=v"(pk2.x) : "v"(p[ct][0]), "v"(p[ct][1]));
            asm("v_cvt_pk_bf16_f32 %0, %1, %2" : "=v"(pk2.y) : "v"(p[ct][2]), "v"(p[ct][3]));
            *(uint2*)&Pw[(lq * 128 + ct * 32 + lk * 8) ^ ((lq & 7) << 4)] = pk2;
        }
        asm volatile("s_waitcnt lgkmcnt(0)" ::: "memory");
        __builtin_amdgcn_sched_barrier(0);

        // ---- O += P V ----
        __builtin_amdgcn_s_setprio(1);
        #pragma unroll
        for (int ks = 0; ks < 2; ++ks) {
            const bf16x8 pf = *(const bf16x8*)&Pw[(lq * 128 + ks * 64 + lk * 16) ^ ((lq & 7) << 4)];
            #pragma unroll
            for (int dt = 0; dt < 4; ++dt) {
                const int dh = dt * 16 + lq;
                const bf16x8 vf = *(const bf16x8*)&Vts[c][(dh * 128 + ks * 64 + lk * 16) ^ VSWZ(dh)];
                o[dt] = __builtin_amdgcn_mfma_f32_16x16x32_bf16(pf, vf, o[dt], 0, 0, 0);
            }
        }
        __builtin_amdgcn_s_setprio(0);

        // ---- write next V tile into other buffer (vmcnt auto-waited) ----
        if (more) {
            #pragma unroll
            for (int j = 0; j < 4; ++j) {
                const int dh = lq * 4 + j;
                const unsigned int pk = (unsigned int)vr[0][j] | ((unsigned int)vr[1][j] << 16);
                *(unsigned int*)&Vts[c ^ 1][(dh * 128 + w * 16 + lk * 4) ^ VSWZ(dh)] = pk;
            }
        }
        __syncthreads();   // one barrier per tile
    }

    // ---- epilogue: O/l -> y hi/lo bf16 ----
    const float inv = 1.0f / l_r;
    float invO[4];
    #pragma unroll
    for (int r = 0; r < 4; ++r) invO[r] = __shfl(inv, lk * 4 + r);
    #pragma unroll
    for (int r = 0; r < 4; ++r) {
        const int row = qt * 128 + w * 16 + lk * 4 + r;
        const size_t base = (size_t)(b * T + row) * D + h * DH;
        #pragma unroll
        for (int dt = 0; dt < 4; ++dt) {
            const float val = o[dt][r] * invO[r];
            const unsigned short hv = f2bf(val);
            yhi[base + dt * 16 + lq] = hv;
            ylo[base + dt * 16 + lq] = f2bf(val - bf2f(hv));
        }
    }
}

// ---------------------------------------------------------------------------
extern "C" void kernel_launch(void* const* d_in, const int* in_sizes, int n_in,
                              void* d_out, int out_size, void* d_ws, size_t ws_size,
                              hipStream_t stream) {
    const float* x     = (const float*)d_in[0];
    const float* w_qkv = (const float*)d_in[1];
    const float* w_out = (const float*)d_in[2];

    unsigned short* Xhi = (unsigned short*)d_ws;              // M*D (reused as Yhi)
    unsigned short* Xlo = Xhi + (size_t)MROWS * D;            // M*D (reused as Ylo)
    unsigned short* Wqh = Xlo + (size_t)MROWS * D;            // 3D*D (N x K)
    unsigned short* Wql = Wqh + (size_t)3 * D * D;
    unsigned short* Woh = Wql + (size_t)3 * D * D;            // D*D
    unsigned short* Wol = Woh + (size_t)D * D;
    unsigned short* QKV = Wol + (size_t)D * D;                // M*3D bf16

    split_f32<<<2048, 256, 0, stream>>>(x, Xhi, Xlo, MROWS * D / 4);
    split_tr<<<dim3(3 * D / 32, D / 32), 256, 0, stream>>>(w_qkv, Wqh, Wql, D, 3 * D);
    split_tr<<<dim3(D / 32, D / 32), 256, 0, stream>>>(w_out, Woh, Wol, D, D);

    // BM=256, BN=128: QKV 24x32=768 blocks (3 full CU rounds), both %8==0
    gemm_split<true><<<dim3(3 * D / 128, MROWS / 256), 512, 0, stream>>>(
        Xhi, Xlo, Wqh, Wql, QKV, MROWS, 3 * D, D);

    attn_mfma<<<dim3(T / 128, B * NH), 512, 0, stream>>>(QKV, Xhi, Xlo);

    // out-proj: 8x32=256 blocks = exactly one full CU round
    gemm_split<false><<<dim3(D / 128, MROWS / 256), 512, 0, stream>>>(
        Xhi, Xlo, Woh, Wol, d_out, MROWS, D, D);
}